// Round 20
// baseline (376.522 us; speedup 1.0000x reference)
//
#include <hip/hip_runtime.h>
#include <hip/hip_bf16.h>

typedef unsigned short u16b;                                   // raw bf16 bits
typedef __attribute__((ext_vector_type(8))) short short8;      // 8 bf16 = 4 VGPR (MFMA A/B frag)
typedef __attribute__((ext_vector_type(4))) float floatx4;     // MFMA C/D frag

#define DEV static __device__ __forceinline__

DEV float sh2f(unsigned short s) { union { unsigned u; float f; } c; c.u = ((unsigned)s) << 16; return c.f; }
DEV unsigned short f2b(float f) {
    unsigned u = __float_as_uint(f);
    u += 0x7FFF + ((u >> 16) & 1);      // RNE to bf16
    return (unsigned short)(u >> 16);
}

// direct global->LDS 16B copy (dest must be linear: wave-uniform base + lane*16)
DEV void gload_lds16(const u16b* g, u16b* l) {
    __builtin_amdgcn_global_load_lds((const __attribute__((address_space(1))) void*)g,
                                     (__attribute__((address_space(3))) void*)l, 16, 0, 0);
}

// packed small-vector offsets (elements) — shared host/device
constexpr int O_LN1G = 0, O_LN1B = 256, O_QB = 512, O_KB = 768, O_VB = 1024,
              O_TB = 1280, O_PB = 1536, O_FFNG = 1792, O_FFNB = 2048,
              O_B1 = 2304, O_B2 = 2560, O_QAB = 2816, O_KAB = 2824,
              O_QAW = 2832, O_KAW = 4880, O_CV = 6928;
constexpr int VALIDC = 51200;            // valid rows (shared host/device)
constexpr int MPANELS = 802;             // qkv m-panels (51328 / 64)

// ---------------------------------------------------------------------------
// Input dtype sniffer. flag[0] = 1 -> inputs are fp32;  0 -> bf16.
// ---------------------------------------------------------------------------
__global__ void detect_k(const unsigned* __restrict__ xw, int* __restrict__ flag) {
    __shared__ int cnt;
    if (threadIdx.x == 0) cnt = 0;
    __syncthreads();
    int my = 0;
    for (int i = threadIdx.x; i < 4096; i += 256) {
        unsigned w = xw[i];
        unsigned e0 = (w >> 7) & 0xFFu;      // low half's bf16 exponent
        if (e0 >= 0xC0u) my++;
    }
    atomicAdd(&cnt, my);
    __syncthreads();
    if (threadIdx.x == 0) flag[0] = (cnt > 64) ? 1 : 0;
}

DEV unsigned short load_cvt(const void* src, size_t idx, int fp32) {
    return fp32 ? f2b(((const float*)src)[idx]) : ((const u16b*)src)[idx];
}

// ---------------------------------------------------------------------------
// Pack + convert the small vectors (gains/biases/qa/ka) into sv (bf16).
// ---------------------------------------------------------------------------
struct VecTab { const void* p[15]; int off[15]; int n[15]; };

__global__ __launch_bounds__(256)
void convert_vecs_k(VecTab tab, const int* __restrict__ flag, u16b* __restrict__ sv) {
    int e = blockIdx.x, fp32 = flag[0];
    const void* s = tab.p[e];
    int n = tab.n[e], off = tab.off[e];
    for (int i = threadIdx.x; i < n; i += 256)
        sv[off + i] = load_cvt(s, i, fp32);
}

// ---------------------------------------------------------------------------
// Batched 256x256 weight transpose: 8 slices, per-slice dst offset + row stride.
// dst[c * rstride + r] = src[r, c]
// ---------------------------------------------------------------------------
struct W8 { const void* p[8]; unsigned dstoff[8]; unsigned rstride[8]; };

__global__ void wtrans_k(W8 tab, u16b* __restrict__ base, const int* __restrict__ flag) {
    __shared__ u16b tile[32][33];
    int fp32 = flag[0];
    const void* src = tab.p[blockIdx.z];
    u16b* dst = base + tab.dstoff[blockIdx.z];
    unsigned rs = tab.rstride[blockIdx.z];
    int c0 = blockIdx.x * 32, r0 = blockIdx.y * 32;
    int tx = threadIdx.x, ty = threadIdx.y;
#pragma unroll
    for (int i = 0; i < 32; i += 8)
        tile[ty + i][tx] = load_cvt(src, (size_t)(r0 + ty + i) * 256 + c0 + tx, fp32);
    __syncthreads();
#pragma unroll
    for (int i = 0; i < 32; i += 8)
        dst[(size_t)(c0 + ty + i) * rs + r0 + tx] = tile[tx][ty + i];
}

// ---------------------------------------------------------------------------
// dtype-converting x transpose in — wide-IO (G13): 4 elems/lane on both
// global sides (8-16 B/lane instead of 2-4 B scalar).
// ---------------------------------------------------------------------------
__global__ __launch_bounds__(256)
void transpose_in_k(const void* __restrict__ src, u16b* __restrict__ dst,
                    int rows, int cols, const int* __restrict__ flag) {
    __shared__ u16b tile[32][36];
    int fp32 = flag[0];
    int c0 = blockIdx.x * 32, r0 = blockIdx.y * 32;
    size_t zb = (size_t)blockIdx.z * rows * cols;
    int tid = threadIdx.x;
    int r = tid >> 3, c4 = (tid & 7) * 4;
    size_t sidx = zb + (size_t)(r0 + r) * cols + c0 + c4;
    if (fp32) {
        const float4 f4 = *(const float4*)((const float*)src + sidx);
        tile[r][c4]     = f2b(f4.x);
        tile[r][c4 + 1] = f2b(f4.y);
        tile[r][c4 + 2] = f2b(f4.z);
        tile[r][c4 + 3] = f2b(f4.w);
    } else {
        *(ushort4*)&tile[r][c4] = *(const ushort4*)((const u16b*)src + sidx);
    }
    __syncthreads();
    int c = tid >> 3, r4 = (tid & 7) * 4;
    ushort4 o;
    o.x = tile[r4][c]; o.y = tile[r4 + 1][c]; o.z = tile[r4 + 2][c]; o.w = tile[r4 + 3][c];
    *(ushort4*)&dst[zb + (size_t)(c0 + c) * rows + r0 + r4] = o;
}

// ---------------------------------------------------------------------------
// cvec[j] = t_b @ p_w[:, j] + p_b[j]  via pT rows (contiguous dot). 1 block.
// ---------------------------------------------------------------------------
__global__ __launch_bounds__(256)
void cvec_k(const u16b* __restrict__ pT, u16b* __restrict__ sv) {
    int j = threadIdx.x;
    float acc = sh2f(sv[O_PB + j]);
    const u16b* row = pT + (size_t)j * 256;
    for (int i = 0; i < 256; i += 8) {
        short8 t8 = *(const short8*)&sv[O_TB + i];
        short8 p8 = *(const short8*)&row[i];
#pragma unroll
        for (int u = 0; u < 8; ++u)
            acc += sh2f((unsigned short)t8[u]) * sh2f((unsigned short)p8[u]);
    }
    sv[O_CV + j] = f2b(acc);
}

// ---------------------------------------------------------------------------
// bf16 GEMM, M-tile = 64.  out[M x N] = A[M x K] @ W (Wt is N x K) + epilogue.
// Staging: B always via global_load_lds (16B direct-to-LDS), A too when
// LNA==0. Bank conflicts broken by XOR swizzle applied BOTH at the per-lane
// global source column and at the fragment read address (rule #21).
// __launch_bounds__(256, 5): LDS 28160 B x 5 = 140.8 KB <= 160 KB and VGPR
// 60 << 102-budget -> 5 blocks/CU (R19 audit: the old (256,4) bound was the
// binding constraint, not LDS/VGPR; occupancy was 34% on a latency-bound
// kernel). Revert to 4 if VGPR_Count jumps past ~100.
// LNA=1: inline LayerNorm with stats computed IN-KERNEL from A.
//        NOTE (R12): do NOT register-cache A across the pre-pass — it
//        spills to scratch (R12: 308 MB, 120 µs).
// LNA=2: combine two partial (sum,sumsq) tables (stats, stats2).
// XY=1: grid (n-blocks, m-blocks) so consecutive blocks share one A-panel.
//       For the (2,800) GEMMs this is optimal: A operands are L3-resident
//       (R15: XCD-pinning them gained nothing and perturbed scheduling).
// XY=2: XCD-pinned panel map (qkv, 6 n-blocks/panel): 1D grid 8*606; block
//       bid -> XCD c=bid&7 under %8 round-robin dispatch; p=c+8*(slot/6),
//       n-slice slot%6 -> all 6 n-blocks of a panel on ONE XCD (R14: -11 µs;
//       R19: qkv FETCH down to 14.7 MB).
// Epilogue goes through LDS (Bs reused as C-tile) -> coalesced uint4 IO.
// STATS=1 (EPI2): per-row (sum,sumsq) over this block's 128 cols -> statOut.
// EPI: 0 = +bias (out stride osParam); 2 = +bias +addm (stride 256);
//      3 = gelu(acc+bias); 4 = +bias tri-split (qkv);
//      5 = +bias +addm, store TRANSPOSED to final (n,256,1600) output.
// ---------------------------------------------------------------------------
template <int EPI, int LNA, int XY = 0, int STATS = 0>
__global__ __launch_bounds__(256, 5)
void gemm256(const u16b* __restrict__ A, int aStride, int K,
             const u16b* __restrict__ Wt,
             const u16b* __restrict__ bias, const u16b* __restrict__ addm,
             u16b* __restrict__ out, size_t osParam,
             const float2* __restrict__ stats, const float2* __restrict__ stats2,
             const u16b* __restrict__ gvec, const u16b* __restrict__ bvec,
             float2* __restrict__ statOut, const int* __restrict__ flag) {
    constexpr bool ALDS = (LNA == 0);        // A staged direct-to-LDS
    __shared__ u16b As[64 * 72];             // stride 72 (VGPR path) / 64 (ALDS)
    __shared__ u16b Bs[8448];                // B stage (128x64 linear) / C-tile (64x132)
    __shared__ float sg[256], sb[256];
    const int tid = threadIdx.x;
    int m0, n0;
    if (XY == 2) {
        int bid = blockIdx.x;
        int c = bid & 7, slot = bid >> 3;    // slot 0..605
        int p = c + 8 * (slot / 6);
        if (p >= MPANELS) return;
        m0 = p * 64;
        n0 = (slot % 6) * 128;
    } else {
        m0 = (XY ? blockIdx.y : blockIdx.x) * 64;
        n0 = (XY ? blockIdx.x : blockIdx.y) * 128;
    }
    const int wv = tid >> 6, lane = tid & 63;
    const int wrow = (wv >> 1) * 32, wcol = (wv & 1) * 64;
    const int fr = lane & 15;            // frag row (m for A, n for B), also C col
    const int fq = lane >> 4;            // quad: k offset fq*8; C row offset fq*4
    floatx4 acc[2][4];
    const floatx4 zero = {0.f, 0.f, 0.f, 0.f};
#pragma unroll
    for (int i = 0; i < 2; ++i)
#pragma unroll
        for (int j = 0; j < 4; ++j) acc[i][j] = zero;

    float2 strow[2];
    if (LNA) {
        sg[tid] = sh2f(gvec[tid]);
        sb[tid] = sh2f(bvec[tid]);
        if (LNA == 1) {
            // in-kernel LN stats: thread's staging rows are tid>>3 and 32+(tid>>3);
            // the row's 8 covering lanes are consecutive -> shfl_xor 1/2/4 reduce.
#pragma unroll
            for (int kk = 0; kk < 2; ++kk) {
                int chunk = tid + kk * 256;
                int row = chunk >> 3, col = (chunk & 7) * 8;
                float s1 = 0.f, s2 = 0.f;
#pragma unroll
                for (int kt2 = 0; kt2 < 256; kt2 += 64) {
                    union { uint4 u; unsigned short h[8]; } rw;
                    rw.u = *(const uint4*)&A[(size_t)(m0 + row) * aStride + kt2 + col];
#pragma unroll
                    for (int j = 0; j < 8; ++j) {
                        float f = sh2f(rw.h[j]);
                        s1 += f; s2 += f * f;
                    }
                }
#pragma unroll
                for (int mm = 1; mm < 8; mm <<= 1) {
                    s1 += __shfl_xor(s1, mm);
                    s2 += __shfl_xor(s2, mm);
                }
                float mean = s1 * (1.f / 256.f);
                float var  = s2 * (1.f / 256.f) - mean * mean;
                strow[kk] = (m0 + row < VALIDC) ? make_float2(mean, rsqrtf(var + 1e-5f))
                                                : make_float2(0.f, 0.f);
            }
        } else {
#pragma unroll
            for (int kk = 0; kk < 2; ++kk) {
                int r = m0 + (tid >> 3) + kk * 32;
                float2 a = stats[r], b = stats2[r];
                float mean = (a.x + b.x) * (1.f / 256.f);
                float var  = (a.y + b.y) * (1.f / 256.f) - mean * mean;
                strow[kk] = make_float2(mean, rsqrtf(var + 1e-5f));
            }
        }
        __syncthreads();
    }

    for (int kt = 0; kt < K; kt += 64) {
        if (ALDS) {
#pragma unroll
            for (int kk = 0; kk < 2; ++kk) {         // A: 512 chunks of 8 elems
                int chunk = tid + kk * 256;
                int row = chunk >> 3, col = (chunk & 7) * 8;
                int scol = col ^ ((row & 7) << 3);   // pre-swizzled source
                gload_lds16(&A[(size_t)(m0 + row) * aStride + kt + scol], &As[chunk * 8]);
            }
        } else {
#pragma unroll
            for (int kk = 0; kk < 2; ++kk) {         // A via VGPR (LN transform)
                int chunk = tid + kk * 256;
                int row = chunk >> 3, col = (chunk & 7) * 8;
                union { uint4 u; unsigned short h[8]; } rw;
                rw.u = *(const uint4*)&A[(size_t)(m0 + row) * aStride + kt + col];
#pragma unroll
                for (int j = 0; j < 8; ++j) {
                    float f = sh2f(rw.h[j]);
                    f = (f - strow[kk].x) * strow[kk].y * sg[kt + col + j] + sb[kt + col + j];
                    rw.h[j] = f2b(f);
                }
                *(uint4*)&As[row * 72 + col] = rw.u;
            }
        }
#pragma unroll
        for (int kk = 0; kk < 4; ++kk) {             // B: 1024 chunks of 8 elems
            int chunk = tid + kk * 256;
            int row = chunk >> 3, col = (chunk & 7) * 8;
            int scol = col ^ ((row & 7) << 3);
            gload_lds16(&Wt[(size_t)(n0 + row) * K + kt + scol], &Bs[chunk * 8]);
        }
        __syncthreads();
#pragma unroll
        for (int s = 0; s < 2; ++s) {
            short8 af[2], bfr[4];
#pragma unroll
            for (int i = 0; i < 2; ++i) {
                int ar = wrow + i * 16 + fr;
                if (ALDS)
                    af[i] = *(const short8*)((const char*)As +
                              ((ar * 128 + s * 64 + fq * 16) ^ ((ar & 7) << 4)));
                else
                    af[i] = *(short8*)&As[ar * 72 + s * 32 + fq * 8];
            }
#pragma unroll
            for (int j = 0; j < 4; ++j) {
                int br = wcol + j * 16 + fr;
                bfr[j] = *(const short8*)((const char*)Bs +
                          ((br * 128 + s * 64 + fq * 16) ^ ((br & 7) << 4)));
            }
#pragma unroll
            for (int i = 0; i < 2; ++i)
#pragma unroll
                for (int j = 0; j < 4; ++j)
                    acc[i][j] = __builtin_amdgcn_mfma_f32_16x16x32_bf16(af[i], bfr[j], acc[i][j], 0, 0, 0);
        }
        __syncthreads();
    }
    // ---- epilogue; C/D layout: col = lane&15, row = (lane>>4)*4 + reg ----
    float bv[4];
#pragma unroll
    for (int j = 0; j < 4; ++j) bv[j] = bias ? sh2f(bias[n0 + wcol + j * 16 + fr]) : 0.f;

    if (EPI == 5) {
        // stage addm tile coalesced into Bs, then per-element LDS reads;
        // transposed store: row = n*1600+tv  ->  d_out[n*409600 + col*1600 + tv]
        u16b* CT = Bs;
#pragma unroll
        for (int kk = 0; kk < 4; ++kk) {
            int chunk = tid + kk * 256;
            int row = chunk >> 4, c8 = (chunk & 15) * 8;
            *(uint4*)&CT[row * 132 + c8] = *(const uint4*)&addm[(size_t)(m0 + row) * 256 + n0 + c8];
        }
        __syncthreads();
        int fp32o = flag[0];
#pragma unroll
        for (int i = 0; i < 2; ++i) {
            int lr0 = wrow + i * 16 + fq * 4;        // local row base
            int row0 = m0 + lr0;
            int n = row0 / 1600;                 // 4-row group never straddles n
            int tv = row0 - n * 1600;
#pragma unroll
            for (int j = 0; j < 4; ++j) {
                int lc = wcol + j * 16 + fr;
                int col = n0 + lc;
                float v4[4];
#pragma unroll
                for (int r = 0; r < 4; ++r)
                    v4[r] = acc[i][j][r] + bv[j] + sh2f(CT[(lr0 + r) * 132 + lc]);
                size_t oidx = ((size_t)n * 256 + col) * 1600 + tv;
                if (fp32o) {
                    float4 o = {v4[0], v4[1], v4[2], v4[3]};
                    *(float4*)((float*)out + oidx) = o;
                } else {
                    ushort4 o;
                    o.x = f2b(v4[0]); o.y = f2b(v4[1]); o.z = f2b(v4[2]); o.w = f2b(v4[3]);
                    *(ushort4*)&out[oidx] = o;
                }
            }
        }
    } else if (EPI == 2) {
        // f32 half-tile CT: exact addm add + stats, round once, coalesced IO
        float* CTf = (float*)Bs;                 // 32*132 f32 = 16896 B = |Bs|
#pragma unroll
        for (int half = 0; half < 2; ++half) {
            if ((wrow >> 5) == half) {
#pragma unroll
                for (int i = 0; i < 2; ++i)
#pragma unroll
                    for (int r = 0; r < 4; ++r) {
                        int lrow = i * 16 + fq * 4 + r;   // 0..31
#pragma unroll
                        for (int j = 0; j < 4; ++j)
                            CTf[lrow * 132 + wcol + j * 16 + fr] = acc[i][j][r] + bv[j];
                    }
            }
            __syncthreads();
#pragma unroll
            for (int kk = 0; kk < 2; ++kk) {
                int chunk = tid + kk * 256;          // 512 chunks of 8
                int row = chunk >> 4, c8 = (chunk & 15) * 8;
                int grow = m0 + half * 32 + row, gcol = n0 + c8;
                union { uint4 u; unsigned short h[8]; } am, ow;
                am.u = *(const uint4*)&addm[(size_t)grow * 256 + gcol];
                float s1 = 0.f, s2 = 0.f;
#pragma unroll
                for (int u8 = 0; u8 < 8; ++u8) {
                    float v = CTf[row * 132 + c8 + u8] + sh2f(am.h[u8]);
                    s1 += v; s2 += v * v;
                    ow.h[u8] = f2b(v);
                }
                if (STATS) {
#pragma unroll
                    for (int mm = 1; mm < 16; mm <<= 1) {
                        s1 += __shfl_xor(s1, mm);
                        s2 += __shfl_xor(s2, mm);
                    }
                    if ((tid & 15) == 0)
                        statOut[(size_t)(n0 >> 7) * 51200 + grow] = make_float2(s1, s2);
                }
                *(uint4*)&out[(size_t)grow * 256 + gcol] = ow.u;
            }
            __syncthreads();
        }
    } else {
        // EPI 0/3/4: pre-round into u16 CT (bit-identical math), coalesced store
        u16b* CT = Bs;
#pragma unroll
        for (int i = 0; i < 2; ++i)
#pragma unroll
            for (int r = 0; r < 4; ++r) {
                int lrow = wrow + i * 16 + fq * 4 + r;
#pragma unroll
                for (int j = 0; j < 4; ++j) {
                    float val = acc[i][j][r] + bv[j];
                    if (EPI == 3) val = 0.5f * val * (1.0f + erff(val * 0.70710678118654752f));
                    CT[lrow * 132 + wcol + j * 16 + fr] = f2b(val);
                }
            }
        __syncthreads();
#pragma unroll
        for (int kk = 0; kk < 4; ++kk) {
            int chunk = tid + kk * 256;              // 1024 chunks of 8
            int row = chunk >> 4, c8 = (chunk & 15) * 8;
            int grow = m0 + row, gcol = n0 + c8;
            uint4 cw = *(const uint4*)&CT[row * 132 + c8];
            if (EPI == 4)      *(uint4*)&out[(size_t)(gcol >> 8) * osParam + (size_t)grow * 256 + (gcol & 255)] = cw;
            else               *(uint4*)&out[(size_t)grow * osParam + gcol] = cw;
        }
    }
}

// ===========================================================================
// pool_fused2: t-pair tiled pooling. One block per (n, t0=2*tp), 512 threads.
// Union window = 6 t-values x 25 v = 150 rows (+10 padded: srow clamp-valid,
// weights zero). Phases (~11 barriers): setup | q-logits MFMA | softmax |
// q-sweep + qbar | reduce->pq | k-su | k-logits | softmax | k-sweep |
// reduce->pk | vbar.  All gather loops use FIXED trip counts so the
// scheduler can overlap loads (R17: sweep fix -7%; R19: logits dual-chain
// -7% on this kernel).
// ===========================================================================

// one 16-row logits fragment: K-accumulation split into two independent
// even/odd MFMA chains (depth 4 instead of 8; f32 reorder on the final add)
DEV floatx4 logits_frag(const u16b* __restrict__ S, const u16b* su,
                        const int* srow, int f, int fr, int fq) {
    floatx4 accA = {0.f, 0.f, 0.f, 0.f};
    floatx4 accB = {0.f, 0.f, 0.f, 0.f};
    const u16b* Ar = S + (size_t)srow[f * 16 + fr] * 256;
#pragma unroll
    for (int s = 0; s < 4; ++s) {
        short8 a0 = *(const short8*)&Ar[(2 * s) * 32 + fq * 8];
        short8 b0 = *(const short8*)&su[fr * 260 + (2 * s) * 32 + fq * 8];
        accA = __builtin_amdgcn_mfma_f32_16x16x32_bf16(a0, b0, accA, 0, 0, 0);
        short8 a1 = *(const short8*)&Ar[(2 * s + 1) * 32 + fq * 8];
        short8 b1 = *(const short8*)&su[fr * 260 + (2 * s + 1) * 32 + fq * 8];
        accB = __builtin_amdgcn_mfma_f32_16x16x32_bf16(a1, b1, accB, 0, 0, 0);
    }
    return accA + accB;
}

// logits over the 150-row union. Straight-line: frag wv always, frag wv+8
// for waves 0-1 (uniform branch); both accs computed BEFORE any slog store
// so the independent MFMA chains interleave.
DEV void logits_union(const u16b* __restrict__ S, const u16b* su, const int* srow,
                      float* slog, const u16b* __restrict__ sv, int aboff, int tid) {
    int wv = tid >> 6, lane = tid & 63;
    int fr = lane & 15, fq = lane >> 4;
    float abv = sh2f(sv[aboff + (fr & 7)]);
    floatx4 acc0 = logits_frag(S, su, srow, wv, fr, fq);
    if (wv < 2) {
        floatx4 acc1 = logits_frag(S, su, srow, wv + 8, fr, fq);
#pragma unroll
        for (int r = 0; r < 4; ++r)
            slog[((wv + 8) * 16 + fq * 4 + r) * 19 + fr] = (acc1[r] + abv) * 0.17677669529663687f;
    }
#pragma unroll
    for (int r = 0; r < 4; ++r)
        slog[(wv * 16 + fq * 4 + r) * 19 + fr] = (acc0[r] + abv) * 0.17677669529663687f;
}

// 16 softmaxes (2 t x 8 heads), two per wave. KC: k-stage (cols 0-15).
template <int KC>
DEV void softmax16(const float* slog, float* wqA, float* wqB, int tid) {
    int wv = tid >> 6, lane = tid & 63;
#pragma unroll
    for (int c = 0; c < 2; ++c) {
        int combo = wv + c * 8;              // 0..15
        int dt = combo >> 3, h = combo & 7;
        int col = KC ? combo : h;
        const float* src = slog + (size_t)(dt * 25) * 19 + col;
        float v0 = (lane < 125) ? src[lane * 19] : -1e30f;
        float v1 = (lane + 64 < 125) ? src[(lane + 64) * 19] : -1e30f;
        float mx = fmaxf(v0, v1);
#pragma unroll
        for (int o = 32; o; o >>= 1) mx = fmaxf(mx, __shfl_xor(mx, o));
        float e0 = (lane < 125) ? __expf(v0 - mx) : 0.f;
        float e1 = (lane + 64 < 125) ? __expf(v1 - mx) : 0.f;
        float s = e0 + e1;
#pragma unroll
        for (int o = 32; o; o >>= 1) s += __shfl_xor(s, o);
        float inv = 1.f / s;
        float* dst = dt ? wqB : wqA;
        int off = dt ? 25 : 0;
        if (lane < 125) dst[(lane + off) * 9 + h] = e0 * inv;
        if (lane + 64 < 125) dst[(lane + 64 + off) * 9 + h] = e1 * inv;
    }
}

// dual-t weighted pool sweep: both t-scratches to disjoint regions, no barrier.
// FIXED 10-iteration trip (u = ls + it*16 <= 159): the weight tables are
// zero-padded to 160 and srow is clamp-valid there, so padded entries add 0.
DEV void pool_sweep2(const u16b* __restrict__ S, const int* srow,
                     const float* wqA, const float* wqB,
                     float* scrA, float* scrB, int tid) {
    int c8 = (tid & 31) * 8, h = c8 >> 5, ls = tid >> 5;
    float a0[8] = {0.f,0.f,0.f,0.f,0.f,0.f,0.f,0.f};
    float a1[8] = {0.f,0.f,0.f,0.f,0.f,0.f,0.f,0.f};
#pragma unroll 2
    for (int it = 0; it < 10; ++it) {
        int u = ls + it * 16;                // 0..159, all table-valid
        float w0 = wqA[u * 9 + h];
        float w1 = wqB[u * 9 + h];
        short8 d8 = *(const short8*)&S[(size_t)srow[u] * 256 + c8];
#pragma unroll
        for (int j = 0; j < 8; ++j) {
            float f = sh2f((unsigned short)d8[j]);
            a0[j] += w0 * f;
            a1[j] += w1 * f;
        }
    }
#pragma unroll
    for (int j = 0; j < 8; ++j) {           // combine the wave's two u-slices
        a0[j] += __shfl_xor(a0[j], 32);
        a1[j] += __shfl_xor(a1[j], 32);
    }
    int wv = tid >> 6, lane = tid & 63;
    if (lane < 32) {
        float4 lo0 = {a0[0], a0[1], a0[2], a0[3]}, hi0 = {a0[4], a0[5], a0[6], a0[7]};
        *(float4*)&scrA[wv * 264 + c8]     = lo0;
        *(float4*)&scrA[wv * 264 + c8 + 4] = hi0;
        float4 lo1 = {a1[0], a1[1], a1[2], a1[3]}, hi1 = {a1[4], a1[5], a1[6], a1[7]};
        *(float4*)&scrB[wv * 260 + c8]     = lo1;
        *(float4*)&scrB[wv * 260 + c8 + 4] = hi1;
    }
}

// concurrent reduction of both scratches (512 threads: halves)
DEV void pool_reduce2(const float* scrA, const float* scrB,
                      float* out0, float* out1, int tid) {
    if (tid < 256) {
        float s = 0.f;
#pragma unroll
        for (int q = 0; q < 8; ++q) s += scrA[q * 264 + tid];
        out0[tid] = s;
    } else {
        int t2 = tid - 256;
        float s = 0.f;
#pragma unroll
        for (int q = 0; q < 8; ++q) s += scrB[q * 260 + t2];
        out1[t2] = s;
    }
}

// window means for both t's from the 6-row union; optional per-c scale.
// FIXED 2-rep trip: rep 1 (i = tid+512, up to 1023) loads unconditionally —
// v <= 31 keeps srow indices <= 156 (clamp-valid) — and only the CB stores
// are guarded (R17 sweep recipe).
DEV void wmean2(const u16b* __restrict__ S, const int* srow,
                const float* scale0, const float* scale1,
                u16b* __restrict__ CB, int base, int nb, int tid) {
#pragma unroll
    for (int rep = 0; rep < 2; ++rep) {
        int i = tid + rep * 512;             // 0..1023
        int v = i >> 5, c8 = (i & 31) * 8;
        float s0[8] = {0.f,0.f,0.f,0.f,0.f,0.f,0.f,0.f};
        float s1[8] = {0.f,0.f,0.f,0.f,0.f,0.f,0.f,0.f};
#pragma unroll
        for (int w = 0; w < 6; ++w) {
            short8 d8 = *(const short8*)&S[(size_t)srow[w * 25 + v] * 256 + c8];
#pragma unroll
            for (int j = 0; j < 8; ++j) {
                float f = sh2f((unsigned short)d8[j]);
                if (w < 5)  s0[j] += f;
                if (w >= 1) s1[j] += f;
            }
        }
        if (i < 800) {
            unsigned short o0[8], o1[8];
#pragma unroll
            for (int j = 0; j < 8; ++j) {
                float m0 = s0[j] * 0.2f, m1 = s1[j] * 0.2f;
                if (scale0) { m0 *= scale0[c8 + j]; m1 *= scale1[c8 + j]; }
                o0[j] = f2b(m0); o1[j] = f2b(m1);
            }
            *(uint4*)&CB[((size_t)nb * 25 + v) * 512 + base + c8]       = *(uint4*)o0;
            *(uint4*)&CB[((size_t)(nb + 1) * 25 + v) * 512 + base + c8] = *(uint4*)o1;
        }
    }
}

__global__ __launch_bounds__(512)
void pool_fused2(const u16b* __restrict__ qf, const u16b* __restrict__ kf,
                 const u16b* __restrict__ vf, const u16b* __restrict__ sv,
                 u16b* __restrict__ CB) {
    __shared__ int srow[160];
    __shared__ alignas(16) u16b su[16 * 260];    // q/k su weights; scrB during sweeps
    __shared__ float slog[160 * 19];             // logits; scrA during sweeps
    __shared__ float wqA[160 * 9], wqB[160 * 9];
    __shared__ float spq[2][256], spk[2][256];
    int bid = blockIdx.x;
    int b2 = ((bid & 7) << 7) | (bid >> 3);  // XCD-aware (1024 % 8 == 0)
    int n = b2 >> 5, t0 = (b2 & 31) * 2;
    int nb = n * 64 + t0;
    int tid = threadIdx.x;
    if (tid < 160) {
        int u = tid < 150 ? tid : 149;
        int tl = u / 25, v = u - tl * 25, tt = t0 + tl - 2;
        srow[tid] = ((unsigned)tt < 64u) ? (n * 64 + tt) * 25 + v : 51200;
    }
    // q su rows 0..7 = qa_w raw copy (layout [c*8+h] -> su[h*260+c]); zero wq once
    for (int i = tid; i < 2048; i += 512) {
        int c = i >> 3, h = i & 7;
        su[h * 260 + c] = sv[O_QAW + i];
    }
    for (int i = tid; i < 1440; i += 512) { wqA[i] = 0.f; wqB[i] = 0.f; }
    __syncthreads();

    // ---- q logits (once per union row, MFMA) + both-t softmax ----
    logits_union(qf, su, srow, slog, sv, O_QAB, tid);
    __syncthreads();
    softmax16<0>(slog, wqA, wqB, tid);
    __syncthreads();

    // ---- q sweep (dual scratch; su dead after logits) + qbar same phase ----
    pool_sweep2(qf, srow, wqA, wqB, slog, (float*)su, tid);
    wmean2(qf, srow, nullptr, nullptr, CB, 256, nb, tid);
    __syncthreads();
    pool_reduce2(slog, (float*)su, spq[0], spq[1], tid);
    __syncthreads();

    // ---- k su: rows 0-7 = ka*pq(t0), rows 8-15 = ka*pq(t1) ----
    for (int i = tid; i < 4096; i += 512) {
        int c = i >> 4, h16 = i & 15;
        float w = sh2f(sv[O_KAW + c * 8 + (h16 & 7)]) * spq[h16 >> 3][c];
        su[h16 * 260 + c] = f2b(w);
    }
    __syncthreads();

    // ---- k logits (both t in one pass: cols 0-15) + softmax ----
    logits_union(kf, su, srow, slog, sv, O_KAB, tid);
    __syncthreads();
    softmax16<1>(slog, wqA, wqB, tid);
    __syncthreads();

    // ---- k sweep (su dead after logits -> scrB) ----
    pool_sweep2(kf, srow, wqA, wqB, slog, (float*)su, tid);
    __syncthreads();
    pool_reduce2(slog, (float*)su, spk[0], spk[1], tid);
    __syncthreads();

    // ---- vbarP for both t -> CB cols 0..255 ----
    wmean2(vf, srow, spk[0], spk[1], CB, 0, nb, tid);
}

// ---------------------------------------------------------------------------
extern "C" void kernel_launch(void* const* d_in, const int* in_sizes, int n_in,
                              void* d_out, int out_size, void* d_ws, size_t ws_size,
                              hipStream_t stream) {
    (void)in_sizes; (void)n_in; (void)out_size; (void)ws_size;
    const void* x    = d_in[0];
    const void* ln1g = d_in[1];  const void* ln1b = d_in[2];
    const void* q_w  = d_in[3];  const void* q_b  = d_in[4];
    const void* qa_w = d_in[5];  const void* qa_b = d_in[6];
    const void* k_w  = d_in[7];  const void* k_b  = d_in[8];
    const void* ka_w = d_in[9];  const void* ka_b = d_in[10];
    const void* v_w  = d_in[11]; const void* v_b  = d_in[12];
    const void* t_w  = d_in[13]; const void* t_b  = d_in[14];
    const void* p_w  = d_in[15]; const void* p_b  = d_in[16];
    const void* ffng = d_in[17]; const void* ffnb = d_in[18];
    const void* w1   = d_in[19]; const void* b1   = d_in[20];
    const void* w2   = d_in[21]; const void* b2   = d_in[22];

    char* ws = (char*)d_ws;
    size_t off = 0;
    auto alloc = [&](size_t bytes) { void* p = ws + off; off += (bytes + 255) & ~(size_t)255; return p; };
    const size_t RPAD = 51328;           // 51200 valid rows + 128 pad rows
    int*    flag = (int*)alloc(256);
    u16b*   sv   = (u16b*)alloc(8192 * 2);                // packed small vectors
    u16b*   wT   = (u16b*)alloc((size_t)7 * 65536 * 2);   // qT kT vT pT tT w1T w2T
    u16b*   cW   = (u16b*)alloc((size_t)256 * 512 * 2);   // comboWt: [TP^T | p_w^T]
    u16b*   xT   = (u16b*)alloc(RPAD * 256 * 2);
    u16b*   Bq   = (u16b*)alloc(RPAD * 256 * 2);          // q_full -> h1
    u16b*   Bk   = (u16b*)alloc(RPAD * 256 * 2);
    u16b*   Bv   = (u16b*)alloc(RPAD * 256 * 2);
    u16b*   CB   = (u16b*)alloc((size_t)51200 * 512 * 2); // [vbarP | qbar]
    u16b*   att  = (u16b*)alloc((size_t)51200 * 256 * 2); // att
    float2* st2p = (float2*)alloc((size_t)2 * 51200 * 8); // att partial stats (2 n-blocks)

    u16b* pT  = wT + 3 * 65536;
    u16b* tT  = wT + 4 * 65536;
    u16b* w1T = wT + 5 * 65536;
    u16b* w2T = wT + 6 * 65536;

    // 0) dtype detection
    detect_k<<<1, 256, 0, stream>>>((const unsigned*)x, flag);
    // 1) small-vector conversion
    VecTab tab;
    const void* vp[15] = {ln1g, ln1b, q_b, k_b, v_b, t_b, p_b, ffng, ffnb, b1, b2, qa_b, ka_b, qa_w, ka_w};
    const int vo[15] = {O_LN1G, O_LN1B, O_QB, O_KB, O_VB, O_TB, O_PB, O_FFNG, O_FFNB, O_B1, O_B2, O_QAB, O_KAB, O_QAW, O_KAW};
    const int vn[15] = {256, 256, 256, 256, 256, 256, 256, 256, 256, 256, 256, 8, 8, 2048, 2048};
    for (int i = 0; i < 15; ++i) { tab.p[i] = vp[i]; tab.off[i] = vo[i]; tab.n[i] = vn[i]; }
    convert_vecs_k<<<15, 256, 0, stream>>>(tab, flag, sv);

    dim3 tb(32, 8);
    // 2) weight transposes: slices 0-6 -> wT slabs; slice 7: p_w^T -> cW cols 256.. (stride 512)
    W8 wt;
    const void* wsrc[8] = {q_w, k_w, v_w, p_w, t_w, w1, w2, p_w};
    for (int i = 0; i < 8; ++i) {
        wt.p[i] = wsrc[i];
        wt.dstoff[i] = (i < 7) ? (unsigned)(i * 65536) : (unsigned)((cW + 256) - wT);
        wt.rstride[i] = (i < 7) ? 256u : 512u;
    }
    wtrans_k<<<dim3(8, 8, 8), tb, 0, stream>>>(wt, wT, flag);
    // 3) cvec = t_b @ p_w + p_b  (into sv+O_CV)
    cvec_k<<<1, 256, 0, stream>>>(pT, sv);
    // 4) TP^T into cW cols 0..255:  out[m,k] = sum_j pT[m,j] tT[k,j] = (t_w@p_w)[k,m]
    gemm256<0, 0><<<dim3(4, 2), 256, 0, stream>>>(pT, 256, 256, tT, nullptr, nullptr,
                                                  cW, 512, nullptr, nullptr, nullptr, nullptr,
                                                  nullptr, nullptr);
    // 5) x (n, 256, 1600) -> xT (n, 1600, 256)
    transpose_in_k<<<dim3(50, 8, 32), 256, 0, stream>>>(x, xT, 256, 1600, flag);
    // 6) fused q/k/v GEMM with inline LN, XCD-pinned panel map (XY=2):
    //    all 6 n-blocks of one A-panel run on ONE XCD -> A fetched once.
    gemm256<4, 1, 2><<<4848, 256, 0, stream>>>(xT, 256, 256, wT, sv + O_QB, nullptr,
                                               Bq, RPAD * 256, nullptr, nullptr,
                                               sv + O_LN1G, sv + O_LN1B, nullptr, nullptr);
    // 7) fused pools + window means (t-pair tiled) -> CB
    pool_fused2<<<1024, 512, 0, stream>>>(Bq, Bk, Bv, sv, CB);
    // 8) att = CB @ comboWt^T + cvec + x_residual (K=512); + partial LN stats -> st2p
    gemm256<2, 0, 1, 1><<<dim3(2, 800), 256, 0, stream>>>(CB, 512, 512, cW, sv + O_CV, xT,
                                                          att, 256, nullptr, nullptr,
                                                          nullptr, nullptr, st2p, nullptr);
    // 9) h1 = gelu(LN(att) @ w1 + b1); LN stats combined from st2p halves (into Bq)
    gemm256<3, 2, 1><<<dim3(2, 800), 256, 0, stream>>>(att, 256, 256, w1T, sv + O_B1, nullptr,
                                                       Bq, 256, st2p, st2p + 51200,
                                                       sv + O_FFNG, sv + O_FFNB, nullptr, nullptr);
    // 10) y = h1 @ w2 + b2 + att, stored transposed directly to output
    gemm256<5, 0, 1><<<dim3(2, 800), 256, 0, stream>>>(Bq, 256, 256, w2T, sv + O_B2, att,
                                                       (u16b*)d_out, 0, nullptr, nullptr,
                                                       nullptr, nullptr, nullptr, flag);
}

// Round 21
// 359.930 us; speedup vs baseline: 1.0461x; 1.0461x over previous
//
#include <hip/hip_runtime.h>
#include <hip/hip_bf16.h>

typedef unsigned short u16b;                                   // raw bf16 bits
typedef __attribute__((ext_vector_type(8))) short short8;      // 8 bf16 = 4 VGPR (MFMA A/B frag)
typedef __attribute__((ext_vector_type(4))) float floatx4;     // MFMA C/D frag

#define DEV static __device__ __forceinline__

DEV float sh2f(unsigned short s) { union { unsigned u; float f; } c; c.u = ((unsigned)s) << 16; return c.f; }
DEV unsigned short f2b(float f) {
    unsigned u = __float_as_uint(f);
    u += 0x7FFF + ((u >> 16) & 1);      // RNE to bf16
    return (unsigned short)(u >> 16);
}

// direct global->LDS 16B copy (dest must be linear: wave-uniform base + lane*16)
DEV void gload_lds16(const u16b* g, u16b* l) {
    __builtin_amdgcn_global_load_lds((const __attribute__((address_space(1))) void*)g,
                                     (__attribute__((address_space(3))) void*)l, 16, 0, 0);
}

// packed small-vector offsets (elements) — shared host/device
constexpr int O_LN1G = 0, O_LN1B = 256, O_QB = 512, O_KB = 768, O_VB = 1024,
              O_TB = 1280, O_PB = 1536, O_FFNG = 1792, O_FFNB = 2048,
              O_B1 = 2304, O_B2 = 2560, O_QAB = 2816, O_KAB = 2824,
              O_QAW = 2832, O_KAW = 4880, O_CV = 6928;
constexpr int VALIDC = 51200;            // valid rows (shared host/device)
constexpr int MPANELS = 802;             // qkv m-panels (51328 / 64)

// ---------------------------------------------------------------------------
// Input dtype sniffer. flag[0] = 1 -> inputs are fp32;  0 -> bf16.
// ---------------------------------------------------------------------------
__global__ void detect_k(const unsigned* __restrict__ xw, int* __restrict__ flag) {
    __shared__ int cnt;
    if (threadIdx.x == 0) cnt = 0;
    __syncthreads();
    int my = 0;
    for (int i = threadIdx.x; i < 4096; i += 256) {
        unsigned w = xw[i];
        unsigned e0 = (w >> 7) & 0xFFu;      // low half's bf16 exponent
        if (e0 >= 0xC0u) my++;
    }
    atomicAdd(&cnt, my);
    __syncthreads();
    if (threadIdx.x == 0) flag[0] = (cnt > 64) ? 1 : 0;
}

DEV unsigned short load_cvt(const void* src, size_t idx, int fp32) {
    return fp32 ? f2b(((const float*)src)[idx]) : ((const u16b*)src)[idx];
}

// ---------------------------------------------------------------------------
// Pack + convert the small vectors (gains/biases/qa/ka) into sv (bf16).
// ---------------------------------------------------------------------------
struct VecTab { const void* p[15]; int off[15]; int n[15]; };

__global__ __launch_bounds__(256)
void convert_vecs_k(VecTab tab, const int* __restrict__ flag, u16b* __restrict__ sv) {
    int e = blockIdx.x, fp32 = flag[0];
    const void* s = tab.p[e];
    int n = tab.n[e], off = tab.off[e];
    for (int i = threadIdx.x; i < n; i += 256)
        sv[off + i] = load_cvt(s, i, fp32);
}

// ---------------------------------------------------------------------------
// Batched 256x256 weight transpose: 8 slices, per-slice dst offset + row stride.
// dst[c * rstride + r] = src[r, c]
// ---------------------------------------------------------------------------
struct W8 { const void* p[8]; unsigned dstoff[8]; unsigned rstride[8]; };

__global__ void wtrans_k(W8 tab, u16b* __restrict__ base, const int* __restrict__ flag) {
    __shared__ u16b tile[32][33];
    int fp32 = flag[0];
    const void* src = tab.p[blockIdx.z];
    u16b* dst = base + tab.dstoff[blockIdx.z];
    unsigned rs = tab.rstride[blockIdx.z];
    int c0 = blockIdx.x * 32, r0 = blockIdx.y * 32;
    int tx = threadIdx.x, ty = threadIdx.y;
#pragma unroll
    for (int i = 0; i < 32; i += 8)
        tile[ty + i][tx] = load_cvt(src, (size_t)(r0 + ty + i) * 256 + c0 + tx, fp32);
    __syncthreads();
#pragma unroll
    for (int i = 0; i < 32; i += 8)
        dst[(size_t)(c0 + ty + i) * rs + r0 + tx] = tile[tx][ty + i];
}

// ---------------------------------------------------------------------------
// dtype-converting x transpose in — wide-IO (G13): 4 elems/lane on both
// global sides (8-16 B/lane instead of 2-4 B scalar).
// ---------------------------------------------------------------------------
__global__ __launch_bounds__(256)
void transpose_in_k(const void* __restrict__ src, u16b* __restrict__ dst,
                    int rows, int cols, const int* __restrict__ flag) {
    __shared__ u16b tile[32][36];
    int fp32 = flag[0];
    int c0 = blockIdx.x * 32, r0 = blockIdx.y * 32;
    size_t zb = (size_t)blockIdx.z * rows * cols;
    int tid = threadIdx.x;
    int r = tid >> 3, c4 = (tid & 7) * 4;
    size_t sidx = zb + (size_t)(r0 + r) * cols + c0 + c4;
    if (fp32) {
        const float4 f4 = *(const float4*)((const float*)src + sidx);
        tile[r][c4]     = f2b(f4.x);
        tile[r][c4 + 1] = f2b(f4.y);
        tile[r][c4 + 2] = f2b(f4.z);
        tile[r][c4 + 3] = f2b(f4.w);
    } else {
        *(ushort4*)&tile[r][c4] = *(const ushort4*)((const u16b*)src + sidx);
    }
    __syncthreads();
    int c = tid >> 3, r4 = (tid & 7) * 4;
    ushort4 o;
    o.x = tile[r4][c]; o.y = tile[r4 + 1][c]; o.z = tile[r4 + 2][c]; o.w = tile[r4 + 3][c];
    *(ushort4*)&dst[zb + (size_t)(c0 + c) * rows + r0 + r4] = o;
}

// ---------------------------------------------------------------------------
// cvec[j] = t_b @ p_w[:, j] + p_b[j]  via pT rows (contiguous dot). 1 block.
// ---------------------------------------------------------------------------
__global__ __launch_bounds__(256)
void cvec_k(const u16b* __restrict__ pT, u16b* __restrict__ sv) {
    int j = threadIdx.x;
    float acc = sh2f(sv[O_PB + j]);
    const u16b* row = pT + (size_t)j * 256;
    for (int i = 0; i < 256; i += 8) {
        short8 t8 = *(const short8*)&sv[O_TB + i];
        short8 p8 = *(const short8*)&row[i];
#pragma unroll
        for (int u = 0; u < 8; ++u)
            acc += sh2f((unsigned short)t8[u]) * sh2f((unsigned short)p8[u]);
    }
    sv[O_CV + j] = f2b(acc);
}

// ---------------------------------------------------------------------------
// bf16 GEMM, M-tile = 64.  out[M x N] = A[M x K] @ W (Wt is N x K) + epilogue.
// Staging: B always via global_load_lds (16B direct-to-LDS), A too when
// LNA==0. Bank conflicts broken by XOR swizzle applied BOTH at the per-lane
// global source column and at the fragment read address (rule #21).
// __launch_bounds__(256, 4): (256,5) REGRESSED (R20: compiler squeezed VGPR
// 60->48, WRITE 77->120 MB of spill traffic, qkv 61->72.5 µs). 4 is right.
// LNA=1: inline LayerNorm with stats computed IN-KERNEL from A.
//        NOTE (R12): do NOT register-cache A across the pre-pass — it
//        spills to scratch (R12: 308 MB, 120 µs).
// LNA=2: combine two partial (sum,sumsq) tables (stats, stats2).
// XY=1: grid (n-blocks, m-blocks) so consecutive blocks share one A-panel.
//       For the (2,800) GEMMs this is optimal: A operands are L3-resident
//       (R15: XCD-pinning them gained nothing and perturbed scheduling).
// XY=2: XCD-pinned panel map (qkv, 6 n-blocks/panel): 1D grid 8*606; block
//       bid -> XCD c=bid&7 under %8 round-robin dispatch; p=c+8*(slot/6),
//       n-slice slot%6 -> all 6 n-blocks of a panel on ONE XCD (R14: -11 µs;
//       R19: qkv FETCH down to 14.7 MB).
// Epilogue goes through LDS (Bs reused as C-tile) -> coalesced uint4 IO.
// STATS=1 (EPI2): per-row (sum,sumsq) over this block's 128 cols -> statOut.
// EPI: 0 = +bias (out stride osParam); 2 = +bias +addm (stride 256);
//      3 = gelu(acc+bias); 4 = +bias tri-split (qkv);
//      5 = +bias +addm, store TRANSPOSED to final (n,256,1600) output.
// ---------------------------------------------------------------------------
template <int EPI, int LNA, int XY = 0, int STATS = 0>
__global__ __launch_bounds__(256, 4)
void gemm256(const u16b* __restrict__ A, int aStride, int K,
             const u16b* __restrict__ Wt,
             const u16b* __restrict__ bias, const u16b* __restrict__ addm,
             u16b* __restrict__ out, size_t osParam,
             const float2* __restrict__ stats, const float2* __restrict__ stats2,
             const u16b* __restrict__ gvec, const u16b* __restrict__ bvec,
             float2* __restrict__ statOut, const int* __restrict__ flag) {
    constexpr bool ALDS = (LNA == 0);        // A staged direct-to-LDS
    __shared__ u16b As[64 * 72];             // stride 72 (VGPR path) / 64 (ALDS)
    __shared__ u16b Bs[8448];                // B stage (128x64 linear) / C-tile (64x132)
    __shared__ float sg[256], sb[256];
    const int tid = threadIdx.x;
    int m0, n0;
    if (XY == 2) {
        int bid = blockIdx.x;
        int c = bid & 7, slot = bid >> 3;    // slot 0..605
        int p = c + 8 * (slot / 6);
        if (p >= MPANELS) return;
        m0 = p * 64;
        n0 = (slot % 6) * 128;
    } else {
        m0 = (XY ? blockIdx.y : blockIdx.x) * 64;
        n0 = (XY ? blockIdx.x : blockIdx.y) * 128;
    }
    const int wv = tid >> 6, lane = tid & 63;
    const int wrow = (wv >> 1) * 32, wcol = (wv & 1) * 64;
    const int fr = lane & 15;            // frag row (m for A, n for B), also C col
    const int fq = lane >> 4;            // quad: k offset fq*8; C row offset fq*4
    floatx4 acc[2][4];
    const floatx4 zero = {0.f, 0.f, 0.f, 0.f};
#pragma unroll
    for (int i = 0; i < 2; ++i)
#pragma unroll
        for (int j = 0; j < 4; ++j) acc[i][j] = zero;

    float2 strow[2];
    if (LNA) {
        sg[tid] = sh2f(gvec[tid]);
        sb[tid] = sh2f(bvec[tid]);
        if (LNA == 1) {
            // in-kernel LN stats: thread's staging rows are tid>>3 and 32+(tid>>3);
            // the row's 8 covering lanes are consecutive -> shfl_xor 1/2/4 reduce.
#pragma unroll
            for (int kk = 0; kk < 2; ++kk) {
                int chunk = tid + kk * 256;
                int row = chunk >> 3, col = (chunk & 7) * 8;
                float s1 = 0.f, s2 = 0.f;
#pragma unroll
                for (int kt2 = 0; kt2 < 256; kt2 += 64) {
                    union { uint4 u; unsigned short h[8]; } rw;
                    rw.u = *(const uint4*)&A[(size_t)(m0 + row) * aStride + kt2 + col];
#pragma unroll
                    for (int j = 0; j < 8; ++j) {
                        float f = sh2f(rw.h[j]);
                        s1 += f; s2 += f * f;
                    }
                }
#pragma unroll
                for (int mm = 1; mm < 8; mm <<= 1) {
                    s1 += __shfl_xor(s1, mm);
                    s2 += __shfl_xor(s2, mm);
                }
                float mean = s1 * (1.f / 256.f);
                float var  = s2 * (1.f / 256.f) - mean * mean;
                strow[kk] = (m0 + row < VALIDC) ? make_float2(mean, rsqrtf(var + 1e-5f))
                                                : make_float2(0.f, 0.f);
            }
        } else {
#pragma unroll
            for (int kk = 0; kk < 2; ++kk) {
                int r = m0 + (tid >> 3) + kk * 32;
                float2 a = stats[r], b = stats2[r];
                float mean = (a.x + b.x) * (1.f / 256.f);
                float var  = (a.y + b.y) * (1.f / 256.f) - mean * mean;
                strow[kk] = make_float2(mean, rsqrtf(var + 1e-5f));
            }
        }
        __syncthreads();
    }

    for (int kt = 0; kt < K; kt += 64) {
        if (ALDS) {
#pragma unroll
            for (int kk = 0; kk < 2; ++kk) {         // A: 512 chunks of 8 elems
                int chunk = tid + kk * 256;
                int row = chunk >> 3, col = (chunk & 7) * 8;
                int scol = col ^ ((row & 7) << 3);   // pre-swizzled source
                gload_lds16(&A[(size_t)(m0 + row) * aStride + kt + scol], &As[chunk * 8]);
            }
        } else {
#pragma unroll
            for (int kk = 0; kk < 2; ++kk) {         // A via VGPR (LN transform)
                int chunk = tid + kk * 256;
                int row = chunk >> 3, col = (chunk & 7) * 8;
                union { uint4 u; unsigned short h[8]; } rw;
                rw.u = *(const uint4*)&A[(size_t)(m0 + row) * aStride + kt + col];
#pragma unroll
                for (int j = 0; j < 8; ++j) {
                    float f = sh2f(rw.h[j]);
                    f = (f - strow[kk].x) * strow[kk].y * sg[kt + col + j] + sb[kt + col + j];
                    rw.h[j] = f2b(f);
                }
                *(uint4*)&As[row * 72 + col] = rw.u;
            }
        }
#pragma unroll
        for (int kk = 0; kk < 4; ++kk) {             // B: 1024 chunks of 8 elems
            int chunk = tid + kk * 256;
            int row = chunk >> 3, col = (chunk & 7) * 8;
            int scol = col ^ ((row & 7) << 3);
            gload_lds16(&Wt[(size_t)(n0 + row) * K + kt + scol], &Bs[chunk * 8]);
        }
        __syncthreads();
#pragma unroll
        for (int s = 0; s < 2; ++s) {
            short8 af[2], bfr[4];
#pragma unroll
            for (int i = 0; i < 2; ++i) {
                int ar = wrow + i * 16 + fr;
                if (ALDS)
                    af[i] = *(const short8*)((const char*)As +
                              ((ar * 128 + s * 64 + fq * 16) ^ ((ar & 7) << 4)));
                else
                    af[i] = *(short8*)&As[ar * 72 + s * 32 + fq * 8];
            }
#pragma unroll
            for (int j = 0; j < 4; ++j) {
                int br = wcol + j * 16 + fr;
                bfr[j] = *(const short8*)((const char*)Bs +
                          ((br * 128 + s * 64 + fq * 16) ^ ((br & 7) << 4)));
            }
#pragma unroll
            for (int i = 0; i < 2; ++i)
#pragma unroll
                for (int j = 0; j < 4; ++j)
                    acc[i][j] = __builtin_amdgcn_mfma_f32_16x16x32_bf16(af[i], bfr[j], acc[i][j], 0, 0, 0);
        }
        __syncthreads();
    }
    // ---- epilogue; C/D layout: col = lane&15, row = (lane>>4)*4 + reg ----
    float bv[4];
#pragma unroll
    for (int j = 0; j < 4; ++j) bv[j] = bias ? sh2f(bias[n0 + wcol + j * 16 + fr]) : 0.f;

    if (EPI == 5) {
        // stage addm tile coalesced into Bs, then per-element LDS reads;
        // transposed store: row = n*1600+tv  ->  d_out[n*409600 + col*1600 + tv]
        u16b* CT = Bs;
#pragma unroll
        for (int kk = 0; kk < 4; ++kk) {
            int chunk = tid + kk * 256;
            int row = chunk >> 4, c8 = (chunk & 15) * 8;
            *(uint4*)&CT[row * 132 + c8] = *(const uint4*)&addm[(size_t)(m0 + row) * 256 + n0 + c8];
        }
        __syncthreads();
        int fp32o = flag[0];
#pragma unroll
        for (int i = 0; i < 2; ++i) {
            int lr0 = wrow + i * 16 + fq * 4;        // local row base
            int row0 = m0 + lr0;
            int n = row0 / 1600;                 // 4-row group never straddles n
            int tv = row0 - n * 1600;
#pragma unroll
            for (int j = 0; j < 4; ++j) {
                int lc = wcol + j * 16 + fr;
                int col = n0 + lc;
                float v4[4];
#pragma unroll
                for (int r = 0; r < 4; ++r)
                    v4[r] = acc[i][j][r] + bv[j] + sh2f(CT[(lr0 + r) * 132 + lc]);
                size_t oidx = ((size_t)n * 256 + col) * 1600 + tv;
                if (fp32o) {
                    float4 o = {v4[0], v4[1], v4[2], v4[3]};
                    *(float4*)((float*)out + oidx) = o;
                } else {
                    ushort4 o;
                    o.x = f2b(v4[0]); o.y = f2b(v4[1]); o.z = f2b(v4[2]); o.w = f2b(v4[3]);
                    *(ushort4*)&out[oidx] = o;
                }
            }
        }
    } else if (EPI == 2) {
        // f32 half-tile CT: exact addm add + stats, round once, coalesced IO
        float* CTf = (float*)Bs;                 // 32*132 f32 = 16896 B = |Bs|
#pragma unroll
        for (int half = 0; half < 2; ++half) {
            if ((wrow >> 5) == half) {
#pragma unroll
                for (int i = 0; i < 2; ++i)
#pragma unroll
                    for (int r = 0; r < 4; ++r) {
                        int lrow = i * 16 + fq * 4 + r;   // 0..31
#pragma unroll
                        for (int j = 0; j < 4; ++j)
                            CTf[lrow * 132 + wcol + j * 16 + fr] = acc[i][j][r] + bv[j];
                    }
            }
            __syncthreads();
#pragma unroll
            for (int kk = 0; kk < 2; ++kk) {
                int chunk = tid + kk * 256;          // 512 chunks of 8
                int row = chunk >> 4, c8 = (chunk & 15) * 8;
                int grow = m0 + half * 32 + row, gcol = n0 + c8;
                union { uint4 u; unsigned short h[8]; } am, ow;
                am.u = *(const uint4*)&addm[(size_t)grow * 256 + gcol];
                float s1 = 0.f, s2 = 0.f;
#pragma unroll
                for (int u8 = 0; u8 < 8; ++u8) {
                    float v = CTf[row * 132 + c8 + u8] + sh2f(am.h[u8]);
                    s1 += v; s2 += v * v;
                    ow.h[u8] = f2b(v);
                }
                if (STATS) {
#pragma unroll
                    for (int mm = 1; mm < 16; mm <<= 1) {
                        s1 += __shfl_xor(s1, mm);
                        s2 += __shfl_xor(s2, mm);
                    }
                    if ((tid & 15) == 0)
                        statOut[(size_t)(n0 >> 7) * 51200 + grow] = make_float2(s1, s2);
                }
                *(uint4*)&out[(size_t)grow * 256 + gcol] = ow.u;
            }
            __syncthreads();
        }
    } else {
        // EPI 0/3/4: pre-round into u16 CT (bit-identical math), coalesced store
        u16b* CT = Bs;
#pragma unroll
        for (int i = 0; i < 2; ++i)
#pragma unroll
            for (int r = 0; r < 4; ++r) {
                int lrow = wrow + i * 16 + fq * 4 + r;
#pragma unroll
                for (int j = 0; j < 4; ++j) {
                    float val = acc[i][j][r] + bv[j];
                    if (EPI == 3) val = 0.5f * val * (1.0f + erff(val * 0.70710678118654752f));
                    CT[lrow * 132 + wcol + j * 16 + fr] = f2b(val);
                }
            }
        __syncthreads();
#pragma unroll
        for (int kk = 0; kk < 4; ++kk) {
            int chunk = tid + kk * 256;              // 1024 chunks of 8
            int row = chunk >> 4, c8 = (chunk & 15) * 8;
            int grow = m0 + row, gcol = n0 + c8;
            uint4 cw = *(const uint4*)&CT[row * 132 + c8];
            if (EPI == 4)      *(uint4*)&out[(size_t)(gcol >> 8) * osParam + (size_t)grow * 256 + (gcol & 255)] = cw;
            else               *(uint4*)&out[(size_t)grow * osParam + gcol] = cw;
        }
    }
}

// ===========================================================================
// pool_fused2: t-pair tiled pooling. One block per (n, t0=2*tp), 512 threads.
// Union window = 6 t-values x 25 v = 150 rows (+10 padded: srow clamp-valid,
// weights zero). Phases (~11 barriers): setup | q-logits MFMA | softmax |
// q-sweep + qbar | reduce->pq | k-su | k-logits | softmax | k-sweep |
// reduce->pk | vbar.  All gather loops use FIXED trip counts so the
// scheduler can overlap loads (R17: sweep fix -7%; R19: logits dual-chain
// -7% on this kernel).
// ===========================================================================

// one 16-row logits fragment: K-accumulation split into two independent
// even/odd MFMA chains (depth 4 instead of 8; f32 reorder on the final add)
DEV floatx4 logits_frag(const u16b* __restrict__ S, const u16b* su,
                        const int* srow, int f, int fr, int fq) {
    floatx4 accA = {0.f, 0.f, 0.f, 0.f};
    floatx4 accB = {0.f, 0.f, 0.f, 0.f};
    const u16b* Ar = S + (size_t)srow[f * 16 + fr] * 256;
#pragma unroll
    for (int s = 0; s < 4; ++s) {
        short8 a0 = *(const short8*)&Ar[(2 * s) * 32 + fq * 8];
        short8 b0 = *(const short8*)&su[fr * 260 + (2 * s) * 32 + fq * 8];
        accA = __builtin_amdgcn_mfma_f32_16x16x32_bf16(a0, b0, accA, 0, 0, 0);
        short8 a1 = *(const short8*)&Ar[(2 * s + 1) * 32 + fq * 8];
        short8 b1 = *(const short8*)&su[fr * 260 + (2 * s + 1) * 32 + fq * 8];
        accB = __builtin_amdgcn_mfma_f32_16x16x32_bf16(a1, b1, accB, 0, 0, 0);
    }
    return accA + accB;
}

// logits over the 150-row union. Straight-line: frag wv always, frag wv+8
// for waves 0-1 (uniform branch); both accs computed BEFORE any slog store
// so the independent MFMA chains interleave.
DEV void logits_union(const u16b* __restrict__ S, const u16b* su, const int* srow,
                      float* slog, const u16b* __restrict__ sv, int aboff, int tid) {
    int wv = tid >> 6, lane = tid & 63;
    int fr = lane & 15, fq = lane >> 4;
    float abv = sh2f(sv[aboff + (fr & 7)]);
    floatx4 acc0 = logits_frag(S, su, srow, wv, fr, fq);
    if (wv < 2) {
        floatx4 acc1 = logits_frag(S, su, srow, wv + 8, fr, fq);
#pragma unroll
        for (int r = 0; r < 4; ++r)
            slog[((wv + 8) * 16 + fq * 4 + r) * 19 + fr] = (acc1[r] + abv) * 0.17677669529663687f;
    }
#pragma unroll
    for (int r = 0; r < 4; ++r)
        slog[(wv * 16 + fq * 4 + r) * 19 + fr] = (acc0[r] + abv) * 0.17677669529663687f;
}

// 16 softmaxes (2 t x 8 heads), two per wave. KC: k-stage (cols 0-15).
template <int KC>
DEV void softmax16(const float* slog, float* wqA, float* wqB, int tid) {
    int wv = tid >> 6, lane = tid & 63;
#pragma unroll
    for (int c = 0; c < 2; ++c) {
        int combo = wv + c * 8;              // 0..15
        int dt = combo >> 3, h = combo & 7;
        int col = KC ? combo : h;
        const float* src = slog + (size_t)(dt * 25) * 19 + col;
        float v0 = (lane < 125) ? src[lane * 19] : -1e30f;
        float v1 = (lane + 64 < 125) ? src[(lane + 64) * 19] : -1e30f;
        float mx = fmaxf(v0, v1);
#pragma unroll
        for (int o = 32; o; o >>= 1) mx = fmaxf(mx, __shfl_xor(mx, o));
        float e0 = (lane < 125) ? __expf(v0 - mx) : 0.f;
        float e1 = (lane + 64 < 125) ? __expf(v1 - mx) : 0.f;
        float s = e0 + e1;
#pragma unroll
        for (int o = 32; o; o >>= 1) s += __shfl_xor(s, o);
        float inv = 1.f / s;
        float* dst = dt ? wqB : wqA;
        int off = dt ? 25 : 0;
        if (lane < 125) dst[(lane + off) * 9 + h] = e0 * inv;
        if (lane + 64 < 125) dst[(lane + 64 + off) * 9 + h] = e1 * inv;
    }
}

// dual-t weighted pool sweep: both t-scratches to disjoint regions, no barrier.
// FIXED 10-iteration trip (u = ls + it*16 <= 159): the weight tables are
// zero-padded to 160 and srow is clamp-valid there, so padded entries add 0.
DEV void pool_sweep2(const u16b* __restrict__ S, const int* srow,
                     const float* wqA, const float* wqB,
                     float* scrA, float* scrB, int tid) {
    int c8 = (tid & 31) * 8, h = c8 >> 5, ls = tid >> 5;
    float a0[8] = {0.f,0.f,0.f,0.f,0.f,0.f,0.f,0.f};
    float a1[8] = {0.f,0.f,0.f,0.f,0.f,0.f,0.f,0.f};
#pragma unroll 2
    for (int it = 0; it < 10; ++it) {
        int u = ls + it * 16;                // 0..159, all table-valid
        float w0 = wqA[u * 9 + h];
        float w1 = wqB[u * 9 + h];
        short8 d8 = *(const short8*)&S[(size_t)srow[u] * 256 + c8];
#pragma unroll
        for (int j = 0; j < 8; ++j) {
            float f = sh2f((unsigned short)d8[j]);
            a0[j] += w0 * f;
            a1[j] += w1 * f;
        }
    }
#pragma unroll
    for (int j = 0; j < 8; ++j) {           // combine the wave's two u-slices
        a0[j] += __shfl_xor(a0[j], 32);
        a1[j] += __shfl_xor(a1[j], 32);
    }
    int wv = tid >> 6, lane = tid & 63;
    if (lane < 32) {
        float4 lo0 = {a0[0], a0[1], a0[2], a0[3]}, hi0 = {a0[4], a0[5], a0[6], a0[7]};
        *(float4*)&scrA[wv * 264 + c8]     = lo0;
        *(float4*)&scrA[wv * 264 + c8 + 4] = hi0;
        float4 lo1 = {a1[0], a1[1], a1[2], a1[3]}, hi1 = {a1[4], a1[5], a1[6], a1[7]};
        *(float4*)&scrB[wv * 260 + c8]     = lo1;
        *(float4*)&scrB[wv * 260 + c8 + 4] = hi1;
    }
}

// concurrent reduction of both scratches (512 threads: halves)
DEV void pool_reduce2(const float* scrA, const float* scrB,
                      float* out0, float* out1, int tid) {
    if (tid < 256) {
        float s = 0.f;
#pragma unroll
        for (int q = 0; q < 8; ++q) s += scrA[q * 264 + tid];
        out0[tid] = s;
    } else {
        int t2 = tid - 256;
        float s = 0.f;
#pragma unroll
        for (int q = 0; q < 8; ++q) s += scrB[q * 260 + t2];
        out1[t2] = s;
    }
}

// window means for both t's from the 6-row union; optional per-c scale.
// FIXED 2-rep trip: rep 1 (i = tid+512, up to 1023) loads unconditionally —
// v <= 31 keeps srow indices <= 156 (clamp-valid) — and only the CB stores
// are guarded (R17 sweep recipe).
DEV void wmean2(const u16b* __restrict__ S, const int* srow,
                const float* scale0, const float* scale1,
                u16b* __restrict__ CB, int base, int nb, int tid) {
#pragma unroll
    for (int rep = 0; rep < 2; ++rep) {
        int i = tid + rep * 512;             // 0..1023
        int v = i >> 5, c8 = (i & 31) * 8;
        float s0[8] = {0.f,0.f,0.f,0.f,0.f,0.f,0.f,0.f};
        float s1[8] = {0.f,0.f,0.f,0.f,0.f,0.f,0.f,0.f};
#pragma unroll
        for (int w = 0; w < 6; ++w) {
            short8 d8 = *(const short8*)&S[(size_t)srow[w * 25 + v] * 256 + c8];
#pragma unroll
            for (int j = 0; j < 8; ++j) {
                float f = sh2f((unsigned short)d8[j]);
                if (w < 5)  s0[j] += f;
                if (w >= 1) s1[j] += f;
            }
        }
        if (i < 800) {
            unsigned short o0[8], o1[8];
#pragma unroll
            for (int j = 0; j < 8; ++j) {
                float m0 = s0[j] * 0.2f, m1 = s1[j] * 0.2f;
                if (scale0) { m0 *= scale0[c8 + j]; m1 *= scale1[c8 + j]; }
                o0[j] = f2b(m0); o1[j] = f2b(m1);
            }
            *(uint4*)&CB[((size_t)nb * 25 + v) * 512 + base + c8]       = *(uint4*)o0;
            *(uint4*)&CB[((size_t)(nb + 1) * 25 + v) * 512 + base + c8] = *(uint4*)o1;
        }
    }
}

__global__ __launch_bounds__(512)
void pool_fused2(const u16b* __restrict__ qf, const u16b* __restrict__ kf,
                 const u16b* __restrict__ vf, const u16b* __restrict__ sv,
                 u16b* __restrict__ CB) {
    __shared__ int srow[160];
    __shared__ alignas(16) u16b su[16 * 260];    // q/k su weights; scrB during sweeps
    __shared__ float slog[160 * 19];             // logits; scrA during sweeps
    __shared__ float wqA[160 * 9], wqB[160 * 9];
    __shared__ float spq[2][256], spk[2][256];
    int bid = blockIdx.x;
    int b2 = ((bid & 7) << 7) | (bid >> 3);  // XCD-aware (1024 % 8 == 0)
    int n = b2 >> 5, t0 = (b2 & 31) * 2;
    int nb = n * 64 + t0;
    int tid = threadIdx.x;
    if (tid < 160) {
        int u = tid < 150 ? tid : 149;
        int tl = u / 25, v = u - tl * 25, tt = t0 + tl - 2;
        srow[tid] = ((unsigned)tt < 64u) ? (n * 64 + tt) * 25 + v : 51200;
    }
    // q su rows 0..7 = qa_w raw copy (layout [c*8+h] -> su[h*260+c]); zero wq once
    for (int i = tid; i < 2048; i += 512) {
        int c = i >> 3, h = i & 7;
        su[h * 260 + c] = sv[O_QAW + i];
    }
    for (int i = tid; i < 1440; i += 512) { wqA[i] = 0.f; wqB[i] = 0.f; }
    __syncthreads();

    // ---- q logits (once per union row, MFMA) + both-t softmax ----
    logits_union(qf, su, srow, slog, sv, O_QAB, tid);
    __syncthreads();
    softmax16<0>(slog, wqA, wqB, tid);
    __syncthreads();

    // ---- q sweep (dual scratch; su dead after logits) + qbar same phase ----
    pool_sweep2(qf, srow, wqA, wqB, slog, (float*)su, tid);
    wmean2(qf, srow, nullptr, nullptr, CB, 256, nb, tid);
    __syncthreads();
    pool_reduce2(slog, (float*)su, spq[0], spq[1], tid);
    __syncthreads();

    // ---- k su: rows 0-7 = ka*pq(t0), rows 8-15 = ka*pq(t1) ----
    for (int i = tid; i < 4096; i += 512) {
        int c = i >> 4, h16 = i & 15;
        float w = sh2f(sv[O_KAW + c * 8 + (h16 & 7)]) * spq[h16 >> 3][c];
        su[h16 * 260 + c] = f2b(w);
    }
    __syncthreads();

    // ---- k logits (both t in one pass: cols 0-15) + softmax ----
    logits_union(kf, su, srow, slog, sv, O_KAB, tid);
    __syncthreads();
    softmax16<1>(slog, wqA, wqB, tid);
    __syncthreads();

    // ---- k sweep (su dead after logits -> scrB) ----
    pool_sweep2(kf, srow, wqA, wqB, slog, (float*)su, tid);
    __syncthreads();
    pool_reduce2(slog, (float*)su, spk[0], spk[1], tid);
    __syncthreads();

    // ---- vbarP for both t -> CB cols 0..255 ----
    wmean2(vf, srow, spk[0], spk[1], CB, 0, nb, tid);
}

// ---------------------------------------------------------------------------
extern "C" void kernel_launch(void* const* d_in, const int* in_sizes, int n_in,
                              void* d_out, int out_size, void* d_ws, size_t ws_size,
                              hipStream_t stream) {
    (void)in_sizes; (void)n_in; (void)out_size; (void)ws_size;
    const void* x    = d_in[0];
    const void* ln1g = d_in[1];  const void* ln1b = d_in[2];
    const void* q_w  = d_in[3];  const void* q_b  = d_in[4];
    const void* qa_w = d_in[5];  const void* qa_b = d_in[6];
    const void* k_w  = d_in[7];  const void* k_b  = d_in[8];
    const void* ka_w = d_in[9];  const void* ka_b = d_in[10];
    const void* v_w  = d_in[11]; const void* v_b  = d_in[12];
    const void* t_w  = d_in[13]; const void* t_b  = d_in[14];
    const void* p_w  = d_in[15]; const void* p_b  = d_in[16];
    const void* ffng = d_in[17]; const void* ffnb = d_in[18];
    const void* w1   = d_in[19]; const void* b1   = d_in[20];
    const void* w2   = d_in[21]; const void* b2   = d_in[22];

    char* ws = (char*)d_ws;
    size_t off = 0;
    auto alloc = [&](size_t bytes) { void* p = ws + off; off += (bytes + 255) & ~(size_t)255; return p; };
    const size_t RPAD = 51328;           // 51200 valid rows + 128 pad rows
    int*    flag = (int*)alloc(256);
    u16b*   sv   = (u16b*)alloc(8192 * 2);                // packed small vectors
    u16b*   wT   = (u16b*)alloc((size_t)7 * 65536 * 2);   // qT kT vT pT tT w1T w2T
    u16b*   cW   = (u16b*)alloc((size_t)256 * 512 * 2);   // comboWt: [TP^T | p_w^T]
    u16b*   xT   = (u16b*)alloc(RPAD * 256 * 2);
    u16b*   Bq   = (u16b*)alloc(RPAD * 256 * 2);          // q_full -> h1
    u16b*   Bk   = (u16b*)alloc(RPAD * 256 * 2);
    u16b*   Bv   = (u16b*)alloc(RPAD * 256 * 2);
    u16b*   CB   = (u16b*)alloc((size_t)51200 * 512 * 2); // [vbarP | qbar]
    u16b*   att  = (u16b*)alloc((size_t)51200 * 256 * 2); // att
    float2* st2p = (float2*)alloc((size_t)2 * 51200 * 8); // att partial stats (2 n-blocks)

    u16b* pT  = wT + 3 * 65536;
    u16b* tT  = wT + 4 * 65536;
    u16b* w1T = wT + 5 * 65536;
    u16b* w2T = wT + 6 * 65536;

    // 0) dtype detection
    detect_k<<<1, 256, 0, stream>>>((const unsigned*)x, flag);
    // 1) small-vector conversion
    VecTab tab;
    const void* vp[15] = {ln1g, ln1b, q_b, k_b, v_b, t_b, p_b, ffng, ffnb, b1, b2, qa_b, ka_b, qa_w, ka_w};
    const int vo[15] = {O_LN1G, O_LN1B, O_QB, O_KB, O_VB, O_TB, O_PB, O_FFNG, O_FFNB, O_B1, O_B2, O_QAB, O_KAB, O_QAW, O_KAW};
    const int vn[15] = {256, 256, 256, 256, 256, 256, 256, 256, 256, 256, 256, 8, 8, 2048, 2048};
    for (int i = 0; i < 15; ++i) { tab.p[i] = vp[i]; tab.off[i] = vo[i]; tab.n[i] = vn[i]; }
    convert_vecs_k<<<15, 256, 0, stream>>>(tab, flag, sv);

    dim3 tb(32, 8);
    // 2) weight transposes: slices 0-6 -> wT slabs; slice 7: p_w^T -> cW cols 256.. (stride 512)
    W8 wt;
    const void* wsrc[8] = {q_w, k_w, v_w, p_w, t_w, w1, w2, p_w};
    for (int i = 0; i < 8; ++i) {
        wt.p[i] = wsrc[i];
        wt.dstoff[i] = (i < 7) ? (unsigned)(i * 65536) : (unsigned)((cW + 256) - wT);
        wt.rstride[i] = (i < 7) ? 256u : 512u;
    }
    wtrans_k<<<dim3(8, 8, 8), tb, 0, stream>>>(wt, wT, flag);
    // 3) cvec = t_b @ p_w + p_b  (into sv+O_CV)
    cvec_k<<<1, 256, 0, stream>>>(pT, sv);
    // 4) TP^T into cW cols 0..255:  out[m,k] = sum_j pT[m,j] tT[k,j] = (t_w@p_w)[k,m]
    gemm256<0, 0><<<dim3(4, 2), 256, 0, stream>>>(pT, 256, 256, tT, nullptr, nullptr,
                                                  cW, 512, nullptr, nullptr, nullptr, nullptr,
                                                  nullptr, nullptr);
    // 5) x (n, 256, 1600) -> xT (n, 1600, 256)
    transpose_in_k<<<dim3(50, 8, 32), 256, 0, stream>>>(x, xT, 256, 1600, flag);
    // 6) fused q/k/v GEMM with inline LN, XCD-pinned panel map (XY=2):
    //    all 6 n-blocks of one A-panel run on ONE XCD -> A fetched once.
    gemm256<4, 1, 2><<<4848, 256, 0, stream>>>(xT, 256, 256, wT, sv + O_QB, nullptr,
                                               Bq, RPAD * 256, nullptr, nullptr,
                                               sv + O_LN1G, sv + O_LN1B, nullptr, nullptr);
    // 7) fused pools + window means (t-pair tiled) -> CB
    pool_fused2<<<1024, 512, 0, stream>>>(Bq, Bk, Bv, sv, CB);
    // 8) att = CB @ comboWt^T + cvec + x_residual (K=512); + partial LN stats -> st2p
    gemm256<2, 0, 1, 1><<<dim3(2, 800), 256, 0, stream>>>(CB, 512, 512, cW, sv + O_CV, xT,
                                                          att, 256, nullptr, nullptr,
                                                          nullptr, nullptr, st2p, nullptr);
    // 9) h1 = gelu(LN(att) @ w1 + b1); LN stats combined from st2p halves (into Bq)
    gemm256<3, 2, 1><<<dim3(2, 800), 256, 0, stream>>>(att, 256, 256, w1T, sv + O_B1, nullptr,
                                                       Bq, 256, st2p, st2p + 51200,
                                                       sv + O_FFNG, sv + O_FFNB, nullptr, nullptr);
    // 10) y = h1 @ w2 + b2 + att, stored transposed directly to output
    gemm256<5, 0, 1><<<dim3(2, 800), 256, 0, stream>>>(Bq, 256, 256, w2T, sv + O_B2, att,
                                                       (u16b*)d_out, 0, nullptr, nullptr,
                                                       nullptr, nullptr, nullptr, flag);
}

// Round 22
// 354.965 us; speedup vs baseline: 1.0607x; 1.0140x over previous
//
#include <hip/hip_runtime.h>
#include <hip/hip_bf16.h>

typedef unsigned short u16b;                                   // raw bf16 bits
typedef __attribute__((ext_vector_type(8))) short short8;      // 8 bf16 = 4 VGPR (MFMA A/B frag)
typedef __attribute__((ext_vector_type(4))) float floatx4;     // MFMA C/D frag

#define DEV static __device__ __forceinline__

DEV float sh2f(unsigned short s) { union { unsigned u; float f; } c; c.u = ((unsigned)s) << 16; return c.f; }
DEV unsigned short f2b(float f) {
    unsigned u = __float_as_uint(f);
    u += 0x7FFF + ((u >> 16) & 1);      // RNE to bf16
    return (unsigned short)(u >> 16);
}

// packed RNE f32->bf16x2 via the HW convert (low word = a, high word = b);
// bit-identical to f2b for finite values, 1 instr instead of 6 (R22).
DEV unsigned cvt_pk_bf16(float a, float b) {
    unsigned r;
    asm volatile("v_cvt_pk_bf16_f32 %0, %1, %2" : "=v"(r) : "v"(a), "v"(b));
    return r;
}

// direct global->LDS 16B copy (dest must be linear: wave-uniform base + lane*16)
DEV void gload_lds16(const u16b* g, u16b* l) {
    __builtin_amdgcn_global_load_lds((const __attribute__((address_space(1))) void*)g,
                                     (__attribute__((address_space(3))) void*)l, 16, 0, 0);
}

// packed small-vector offsets (elements) — shared host/device
constexpr int O_LN1G = 0, O_LN1B = 256, O_QB = 512, O_KB = 768, O_VB = 1024,
              O_TB = 1280, O_PB = 1536, O_FFNG = 1792, O_FFNB = 2048,
              O_B1 = 2304, O_B2 = 2560, O_QAB = 2816, O_KAB = 2824,
              O_QAW = 2832, O_KAW = 4880, O_CV = 6928;
constexpr int VALIDC = 51200;            // valid rows (shared host/device)
constexpr int MPANELS = 802;             // qkv m-panels (51328 / 64)

// ---------------------------------------------------------------------------
// Input dtype sniffer. flag[0] = 1 -> inputs are fp32;  0 -> bf16.
// ---------------------------------------------------------------------------
__global__ void detect_k(const unsigned* __restrict__ xw, int* __restrict__ flag) {
    __shared__ int cnt;
    if (threadIdx.x == 0) cnt = 0;
    __syncthreads();
    int my = 0;
    for (int i = threadIdx.x; i < 4096; i += 256) {
        unsigned w = xw[i];
        unsigned e0 = (w >> 7) & 0xFFu;      // low half's bf16 exponent
        if (e0 >= 0xC0u) my++;
    }
    atomicAdd(&cnt, my);
    __syncthreads();
    if (threadIdx.x == 0) flag[0] = (cnt > 64) ? 1 : 0;
}

DEV unsigned short load_cvt(const void* src, size_t idx, int fp32) {
    return fp32 ? f2b(((const float*)src)[idx]) : ((const u16b*)src)[idx];
}

// ---------------------------------------------------------------------------
// Pack + convert the small vectors (gains/biases/qa/ka) into sv (bf16).
// ---------------------------------------------------------------------------
struct VecTab { const void* p[15]; int off[15]; int n[15]; };

__global__ __launch_bounds__(256)
void convert_vecs_k(VecTab tab, const int* __restrict__ flag, u16b* __restrict__ sv) {
    int e = blockIdx.x, fp32 = flag[0];
    const void* s = tab.p[e];
    int n = tab.n[e], off = tab.off[e];
    for (int i = threadIdx.x; i < n; i += 256)
        sv[off + i] = load_cvt(s, i, fp32);
}

// ---------------------------------------------------------------------------
// Batched 256x256 weight transpose: 8 slices, per-slice dst offset + row stride.
// dst[c * rstride + r] = src[r, c]
// ---------------------------------------------------------------------------
struct W8 { const void* p[8]; unsigned dstoff[8]; unsigned rstride[8]; };

__global__ void wtrans_k(W8 tab, u16b* __restrict__ base, const int* __restrict__ flag) {
    __shared__ u16b tile[32][33];
    int fp32 = flag[0];
    const void* src = tab.p[blockIdx.z];
    u16b* dst = base + tab.dstoff[blockIdx.z];
    unsigned rs = tab.rstride[blockIdx.z];
    int c0 = blockIdx.x * 32, r0 = blockIdx.y * 32;
    int tx = threadIdx.x, ty = threadIdx.y;
#pragma unroll
    for (int i = 0; i < 32; i += 8)
        tile[ty + i][tx] = load_cvt(src, (size_t)(r0 + ty + i) * 256 + c0 + tx, fp32);
    __syncthreads();
#pragma unroll
    for (int i = 0; i < 32; i += 8)
        dst[(size_t)(c0 + ty + i) * rs + r0 + tx] = tile[tx][ty + i];
}

// ---------------------------------------------------------------------------
// dtype-converting x transpose in — wide-IO (G13): 4 elems/lane on both
// global sides (8-16 B/lane instead of 2-4 B scalar).
// ---------------------------------------------------------------------------
__global__ __launch_bounds__(256)
void transpose_in_k(const void* __restrict__ src, u16b* __restrict__ dst,
                    int rows, int cols, const int* __restrict__ flag) {
    __shared__ u16b tile[32][36];
    int fp32 = flag[0];
    int c0 = blockIdx.x * 32, r0 = blockIdx.y * 32;
    size_t zb = (size_t)blockIdx.z * rows * cols;
    int tid = threadIdx.x;
    int r = tid >> 3, c4 = (tid & 7) * 4;
    size_t sidx = zb + (size_t)(r0 + r) * cols + c0 + c4;
    if (fp32) {
        const float4 f4 = *(const float4*)((const float*)src + sidx);
        tile[r][c4]     = f2b(f4.x);
        tile[r][c4 + 1] = f2b(f4.y);
        tile[r][c4 + 2] = f2b(f4.z);
        tile[r][c4 + 3] = f2b(f4.w);
    } else {
        *(ushort4*)&tile[r][c4] = *(const ushort4*)((const u16b*)src + sidx);
    }
    __syncthreads();
    int c = tid >> 3, r4 = (tid & 7) * 4;
    ushort4 o;
    o.x = tile[r4][c]; o.y = tile[r4 + 1][c]; o.z = tile[r4 + 2][c]; o.w = tile[r4 + 3][c];
    *(ushort4*)&dst[zb + (size_t)(c0 + c) * rows + r0 + r4] = o;
}

// ---------------------------------------------------------------------------
// cvec[j] = t_b @ p_w[:, j] + p_b[j]  via pT rows (contiguous dot). 1 block.
// ---------------------------------------------------------------------------
__global__ __launch_bounds__(256)
void cvec_k(const u16b* __restrict__ pT, u16b* __restrict__ sv) {
    int j = threadIdx.x;
    float acc = sh2f(sv[O_PB + j]);
    const u16b* row = pT + (size_t)j * 256;
    for (int i = 0; i < 256; i += 8) {
        short8 t8 = *(const short8*)&sv[O_TB + i];
        short8 p8 = *(const short8*)&row[i];
#pragma unroll
        for (int u = 0; u < 8; ++u)
            acc += sh2f((unsigned short)t8[u]) * sh2f((unsigned short)p8[u]);
    }
    sv[O_CV + j] = f2b(acc);
}

// ---------------------------------------------------------------------------
// bf16 GEMM, M-tile = 64.  out[M x N] = A[M x K] @ W (Wt is N x K) + epilogue.
// Staging: B always via global_load_lds (16B direct-to-LDS), A too when
// LNA==0. Bank conflicts broken by XOR swizzle applied BOTH at the per-lane
// global source column and at the fragment read address (rule #21).
// __launch_bounds__(256, 4): (256,5) REGRESSED (R20: compiler squeezed VGPR
// 60->48, WRITE 77->120 MB of spill traffic, qkv 61->72.5 µs). 4 is right.
// LNA=1: inline LayerNorm with stats computed IN-KERNEL from A.
//        NOTE (R12): do NOT register-cache A across the pre-pass — it
//        spills to scratch (R12: 308 MB, 120 µs).
//        R22: staging rounds via v_cvt_pk_bf16_f32 (1 instr / 2 elems,
//        bit-identical RNE) instead of 3-op manual bit math.
// LNA=2: combine two partial (sum,sumsq) tables (stats, stats2).
// XY=1: grid (n-blocks, m-blocks) so consecutive blocks share one A-panel.
//       For the (2,800) GEMMs this is optimal: A operands are L3-resident
//       (R15: XCD-pinning them gained nothing and perturbed scheduling).
// XY=2: XCD-pinned panel map (qkv, 6 n-blocks/panel): 1D grid 8*606; block
//       bid -> XCD c=bid&7 under %8 round-robin dispatch; p=c+8*(slot/6),
//       n-slice slot%6 -> all 6 n-blocks of a panel on ONE XCD (R14: -11 µs;
//       R19: qkv FETCH down to 14.7 MB).
// Epilogue goes through LDS (Bs reused as C-tile) -> coalesced uint4 IO.
// STATS=1 (EPI2): per-row (sum,sumsq) over this block's 128 cols -> statOut.
// EPI: 0 = +bias (out stride osParam); 2 = +bias +addm (stride 256);
//      3 = gelu(acc+bias); 4 = +bias tri-split (qkv);
//      5 = +bias +addm, store TRANSPOSED to final (n,256,1600) output.
// ---------------------------------------------------------------------------
template <int EPI, int LNA, int XY = 0, int STATS = 0>
__global__ __launch_bounds__(256, 4)
void gemm256(const u16b* __restrict__ A, int aStride, int K,
             const u16b* __restrict__ Wt,
             const u16b* __restrict__ bias, const u16b* __restrict__ addm,
             u16b* __restrict__ out, size_t osParam,
             const float2* __restrict__ stats, const float2* __restrict__ stats2,
             const u16b* __restrict__ gvec, const u16b* __restrict__ bvec,
             float2* __restrict__ statOut, const int* __restrict__ flag) {
    constexpr bool ALDS = (LNA == 0);        // A staged direct-to-LDS
    __shared__ u16b As[64 * 72];             // stride 72 (VGPR path) / 64 (ALDS)
    __shared__ u16b Bs[8448];                // B stage (128x64 linear) / C-tile (64x132)
    __shared__ float sg[256], sb[256];
    const int tid = threadIdx.x;
    int m0, n0;
    if (XY == 2) {
        int bid = blockIdx.x;
        int c = bid & 7, slot = bid >> 3;    // slot 0..605
        int p = c + 8 * (slot / 6);
        if (p >= MPANELS) return;
        m0 = p * 64;
        n0 = (slot % 6) * 128;
    } else {
        m0 = (XY ? blockIdx.y : blockIdx.x) * 64;
        n0 = (XY ? blockIdx.x : blockIdx.y) * 128;
    }
    const int wv = tid >> 6, lane = tid & 63;
    const int wrow = (wv >> 1) * 32, wcol = (wv & 1) * 64;
    const int fr = lane & 15;            // frag row (m for A, n for B), also C col
    const int fq = lane >> 4;            // quad: k offset fq*8; C row offset fq*4
    floatx4 acc[2][4];
    const floatx4 zero = {0.f, 0.f, 0.f, 0.f};
#pragma unroll
    for (int i = 0; i < 2; ++i)
#pragma unroll
        for (int j = 0; j < 4; ++j) acc[i][j] = zero;

    float2 strow[2];
    if (LNA) {
        sg[tid] = sh2f(gvec[tid]);
        sb[tid] = sh2f(bvec[tid]);
        if (LNA == 1) {
            // in-kernel LN stats: thread's staging rows are tid>>3 and 32+(tid>>3);
            // the row's 8 covering lanes are consecutive -> shfl_xor 1/2/4 reduce.
#pragma unroll
            for (int kk = 0; kk < 2; ++kk) {
                int chunk = tid + kk * 256;
                int row = chunk >> 3, col = (chunk & 7) * 8;
                float s1 = 0.f, s2 = 0.f;
#pragma unroll
                for (int kt2 = 0; kt2 < 256; kt2 += 64) {
                    union { uint4 u; unsigned short h[8]; } rw;
                    rw.u = *(const uint4*)&A[(size_t)(m0 + row) * aStride + kt2 + col];
#pragma unroll
                    for (int j = 0; j < 8; ++j) {
                        float f = sh2f(rw.h[j]);
                        s1 += f; s2 += f * f;
                    }
                }
#pragma unroll
                for (int mm = 1; mm < 8; mm <<= 1) {
                    s1 += __shfl_xor(s1, mm);
                    s2 += __shfl_xor(s2, mm);
                }
                float mean = s1 * (1.f / 256.f);
                float var  = s2 * (1.f / 256.f) - mean * mean;
                strow[kk] = (m0 + row < VALIDC) ? make_float2(mean, rsqrtf(var + 1e-5f))
                                                : make_float2(0.f, 0.f);
            }
        } else {
#pragma unroll
            for (int kk = 0; kk < 2; ++kk) {
                int r = m0 + (tid >> 3) + kk * 32;
                float2 a = stats[r], b = stats2[r];
                float mean = (a.x + b.x) * (1.f / 256.f);
                float var  = (a.y + b.y) * (1.f / 256.f) - mean * mean;
                strow[kk] = make_float2(mean, rsqrtf(var + 1e-5f));
            }
        }
        __syncthreads();
    }

    for (int kt = 0; kt < K; kt += 64) {
        if (ALDS) {
#pragma unroll
            for (int kk = 0; kk < 2; ++kk) {         // A: 512 chunks of 8 elems
                int chunk = tid + kk * 256;
                int row = chunk >> 3, col = (chunk & 7) * 8;
                int scol = col ^ ((row & 7) << 3);   // pre-swizzled source
                gload_lds16(&A[(size_t)(m0 + row) * aStride + kt + scol], &As[chunk * 8]);
            }
        } else {
#pragma unroll
            for (int kk = 0; kk < 2; ++kk) {         // A via VGPR (LN transform)
                int chunk = tid + kk * 256;
                int row = chunk >> 3, col = (chunk & 7) * 8;
                union { uint4 u; unsigned short h[8]; } rw;
                rw.u = *(const uint4*)&A[(size_t)(m0 + row) * aStride + kt + col];
                float f[8];
#pragma unroll
                for (int j = 0; j < 8; ++j)
                    f[j] = (sh2f(rw.h[j]) - strow[kk].x) * strow[kk].y * sg[kt + col + j] + sb[kt + col + j];
                uint4 w;
                w.x = cvt_pk_bf16(f[0], f[1]);
                w.y = cvt_pk_bf16(f[2], f[3]);
                w.z = cvt_pk_bf16(f[4], f[5]);
                w.w = cvt_pk_bf16(f[6], f[7]);
                *(uint4*)&As[row * 72 + col] = w;
            }
        }
#pragma unroll
        for (int kk = 0; kk < 4; ++kk) {             // B: 1024 chunks of 8 elems
            int chunk = tid + kk * 256;
            int row = chunk >> 3, col = (chunk & 7) * 8;
            int scol = col ^ ((row & 7) << 3);
            gload_lds16(&Wt[(size_t)(n0 + row) * K + kt + scol], &Bs[chunk * 8]);
        }
        __syncthreads();
#pragma unroll
        for (int s = 0; s < 2; ++s) {
            short8 af[2], bfr[4];
#pragma unroll
            for (int i = 0; i < 2; ++i) {
                int ar = wrow + i * 16 + fr;
                if (ALDS)
                    af[i] = *(const short8*)((const char*)As +
                              ((ar * 128 + s * 64 + fq * 16) ^ ((ar & 7) << 4)));
                else
                    af[i] = *(short8*)&As[ar * 72 + s * 32 + fq * 8];
            }
#pragma unroll
            for (int j = 0; j < 4; ++j) {
                int br = wcol + j * 16 + fr;
                bfr[j] = *(const short8*)((const char*)Bs +
                          ((br * 128 + s * 64 + fq * 16) ^ ((br & 7) << 4)));
            }
#pragma unroll
            for (int i = 0; i < 2; ++i)
#pragma unroll
                for (int j = 0; j < 4; ++j)
                    acc[i][j] = __builtin_amdgcn_mfma_f32_16x16x32_bf16(af[i], bfr[j], acc[i][j], 0, 0, 0);
        }
        __syncthreads();
    }
    // ---- epilogue; C/D layout: col = lane&15, row = (lane>>4)*4 + reg ----
    float bv[4];
#pragma unroll
    for (int j = 0; j < 4; ++j) bv[j] = bias ? sh2f(bias[n0 + wcol + j * 16 + fr]) : 0.f;

    if (EPI == 5) {
        // stage addm tile coalesced into Bs, then per-element LDS reads;
        // transposed store: row = n*1600+tv  ->  d_out[n*409600 + col*1600 + tv]
        u16b* CT = Bs;
#pragma unroll
        for (int kk = 0; kk < 4; ++kk) {
            int chunk = tid + kk * 256;
            int row = chunk >> 4, c8 = (chunk & 15) * 8;
            *(uint4*)&CT[row * 132 + c8] = *(const uint4*)&addm[(size_t)(m0 + row) * 256 + n0 + c8];
        }
        __syncthreads();
        int fp32o = flag[0];
#pragma unroll
        for (int i = 0; i < 2; ++i) {
            int lr0 = wrow + i * 16 + fq * 4;        // local row base
            int row0 = m0 + lr0;
            int n = row0 / 1600;                 // 4-row group never straddles n
            int tv = row0 - n * 1600;
#pragma unroll
            for (int j = 0; j < 4; ++j) {
                int lc = wcol + j * 16 + fr;
                int col = n0 + lc;
                float v4[4];
#pragma unroll
                for (int r = 0; r < 4; ++r)
                    v4[r] = acc[i][j][r] + bv[j] + sh2f(CT[(lr0 + r) * 132 + lc]);
                size_t oidx = ((size_t)n * 256 + col) * 1600 + tv;
                if (fp32o) {
                    float4 o = {v4[0], v4[1], v4[2], v4[3]};
                    *(float4*)((float*)out + oidx) = o;
                } else {
                    ushort4 o;
                    o.x = f2b(v4[0]); o.y = f2b(v4[1]); o.z = f2b(v4[2]); o.w = f2b(v4[3]);
                    *(ushort4*)&out[oidx] = o;
                }
            }
        }
    } else if (EPI == 2) {
        // f32 half-tile CT: exact addm add + stats, round once, coalesced IO
        float* CTf = (float*)Bs;                 // 32*132 f32 = 16896 B = |Bs|
#pragma unroll
        for (int half = 0; half < 2; ++half) {
            if ((wrow >> 5) == half) {
#pragma unroll
                for (int i = 0; i < 2; ++i)
#pragma unroll
                    for (int r = 0; r < 4; ++r) {
                        int lrow = i * 16 + fq * 4 + r;   // 0..31
#pragma unroll
                        for (int j = 0; j < 4; ++j)
                            CTf[lrow * 132 + wcol + j * 16 + fr] = acc[i][j][r] + bv[j];
                    }
            }
            __syncthreads();
#pragma unroll
            for (int kk = 0; kk < 2; ++kk) {
                int chunk = tid + kk * 256;          // 512 chunks of 8
                int row = chunk >> 4, c8 = (chunk & 15) * 8;
                int grow = m0 + half * 32 + row, gcol = n0 + c8;
                union { uint4 u; unsigned short h[8]; } am, ow;
                am.u = *(const uint4*)&addm[(size_t)grow * 256 + gcol];
                float s1 = 0.f, s2 = 0.f;
#pragma unroll
                for (int u8 = 0; u8 < 8; ++u8) {
                    float v = CTf[row * 132 + c8 + u8] + sh2f(am.h[u8]);
                    s1 += v; s2 += v * v;
                    ow.h[u8] = f2b(v);
                }
                if (STATS) {
#pragma unroll
                    for (int mm = 1; mm < 16; mm <<= 1) {
                        s1 += __shfl_xor(s1, mm);
                        s2 += __shfl_xor(s2, mm);
                    }
                    if ((tid & 15) == 0)
                        statOut[(size_t)(n0 >> 7) * 51200 + grow] = make_float2(s1, s2);
                }
                *(uint4*)&out[(size_t)grow * 256 + gcol] = ow.u;
            }
            __syncthreads();
        }
    } else {
        // EPI 0/3/4: pre-round into u16 CT (bit-identical math), coalesced store
        u16b* CT = Bs;
#pragma unroll
        for (int i = 0; i < 2; ++i)
#pragma unroll
            for (int r = 0; r < 4; ++r) {
                int lrow = wrow + i * 16 + fq * 4 + r;
#pragma unroll
                for (int j = 0; j < 4; ++j) {
                    float val = acc[i][j][r] + bv[j];
                    if (EPI == 3) val = 0.5f * val * (1.0f + erff(val * 0.70710678118654752f));
                    CT[lrow * 132 + wcol + j * 16 + fr] = f2b(val);
                }
            }
        __syncthreads();
#pragma unroll
        for (int kk = 0; kk < 4; ++kk) {
            int chunk = tid + kk * 256;              // 1024 chunks of 8
            int row = chunk >> 4, c8 = (chunk & 15) * 8;
            int grow = m0 + row, gcol = n0 + c8;
            uint4 cw = *(const uint4*)&CT[row * 132 + c8];
            if (EPI == 4)      *(uint4*)&out[(size_t)(gcol >> 8) * osParam + (size_t)grow * 256 + (gcol & 255)] = cw;
            else               *(uint4*)&out[(size_t)grow * osParam + gcol] = cw;
        }
    }
}

// ===========================================================================
// pool_fused2: t-pair tiled pooling. One block per (n, t0=2*tp), 512 threads.
// Union window = 6 t-values x 25 v = 150 rows (+10 padded: srow clamp-valid,
// weights zero). Phases (~11 barriers): setup | q-logits MFMA | softmax |
// q-sweep + qbar | reduce->pq | k-su | k-logits | softmax | k-sweep |
// reduce->pk | vbar.  All gather loops use FIXED trip counts so the
// scheduler can overlap loads (R17: sweep fix -7%; R19: logits dual-chain
// -7% on this kernel).
// ===========================================================================

// one 16-row logits fragment: K-accumulation split into two independent
// even/odd MFMA chains (depth 4 instead of 8; f32 reorder on the final add)
DEV floatx4 logits_frag(const u16b* __restrict__ S, const u16b* su,
                        const int* srow, int f, int fr, int fq) {
    floatx4 accA = {0.f, 0.f, 0.f, 0.f};
    floatx4 accB = {0.f, 0.f, 0.f, 0.f};
    const u16b* Ar = S + (size_t)srow[f * 16 + fr] * 256;
#pragma unroll
    for (int s = 0; s < 4; ++s) {
        short8 a0 = *(const short8*)&Ar[(2 * s) * 32 + fq * 8];
        short8 b0 = *(const short8*)&su[fr * 260 + (2 * s) * 32 + fq * 8];
        accA = __builtin_amdgcn_mfma_f32_16x16x32_bf16(a0, b0, accA, 0, 0, 0);
        short8 a1 = *(const short8*)&Ar[(2 * s + 1) * 32 + fq * 8];
        short8 b1 = *(const short8*)&su[fr * 260 + (2 * s + 1) * 32 + fq * 8];
        accB = __builtin_amdgcn_mfma_f32_16x16x32_bf16(a1, b1, accB, 0, 0, 0);
    }
    return accA + accB;
}

// logits over the 150-row union. Straight-line: frag wv always, frag wv+8
// for waves 0-1 (uniform branch); both accs computed BEFORE any slog store
// so the independent MFMA chains interleave.
DEV void logits_union(const u16b* __restrict__ S, const u16b* su, const int* srow,
                      float* slog, const u16b* __restrict__ sv, int aboff, int tid) {
    int wv = tid >> 6, lane = tid & 63;
    int fr = lane & 15, fq = lane >> 4;
    float abv = sh2f(sv[aboff + (fr & 7)]);
    floatx4 acc0 = logits_frag(S, su, srow, wv, fr, fq);
    if (wv < 2) {
        floatx4 acc1 = logits_frag(S, su, srow, wv + 8, fr, fq);
#pragma unroll
        for (int r = 0; r < 4; ++r)
            slog[((wv + 8) * 16 + fq * 4 + r) * 19 + fr] = (acc1[r] + abv) * 0.17677669529663687f;
    }
#pragma unroll
    for (int r = 0; r < 4; ++r)
        slog[(wv * 16 + fq * 4 + r) * 19 + fr] = (acc0[r] + abv) * 0.17677669529663687f;
}

// 16 softmaxes (2 t x 8 heads), two per wave. KC: k-stage (cols 0-15).
template <int KC>
DEV void softmax16(const float* slog, float* wqA, float* wqB, int tid) {
    int wv = tid >> 6, lane = tid & 63;
#pragma unroll
    for (int c = 0; c < 2; ++c) {
        int combo = wv + c * 8;              // 0..15
        int dt = combo >> 3, h = combo & 7;
        int col = KC ? combo : h;
        const float* src = slog + (size_t)(dt * 25) * 19 + col;
        float v0 = (lane < 125) ? src[lane * 19] : -1e30f;
        float v1 = (lane + 64 < 125) ? src[(lane + 64) * 19] : -1e30f;
        float mx = fmaxf(v0, v1);
#pragma unroll
        for (int o = 32; o; o >>= 1) mx = fmaxf(mx, __shfl_xor(mx, o));
        float e0 = (lane < 125) ? __expf(v0 - mx) : 0.f;
        float e1 = (lane + 64 < 125) ? __expf(v1 - mx) : 0.f;
        float s = e0 + e1;
#pragma unroll
        for (int o = 32; o; o >>= 1) s += __shfl_xor(s, o);
        float inv = 1.f / s;
        float* dst = dt ? wqB : wqA;
        int off = dt ? 25 : 0;
        if (lane < 125) dst[(lane + off) * 9 + h] = e0 * inv;
        if (lane + 64 < 125) dst[(lane + 64 + off) * 9 + h] = e1 * inv;
    }
}

// dual-t weighted pool sweep: both t-scratches to disjoint regions, no barrier.
// FIXED 10-iteration trip (u = ls + it*16 <= 159): the weight tables are
// zero-padded to 160 and srow is clamp-valid there, so padded entries add 0.
DEV void pool_sweep2(const u16b* __restrict__ S, const int* srow,
                     const float* wqA, const float* wqB,
                     float* scrA, float* scrB, int tid) {
    int c8 = (tid & 31) * 8, h = c8 >> 5, ls = tid >> 5;
    float a0[8] = {0.f,0.f,0.f,0.f,0.f,0.f,0.f,0.f};
    float a1[8] = {0.f,0.f,0.f,0.f,0.f,0.f,0.f,0.f};
#pragma unroll 2
    for (int it = 0; it < 10; ++it) {
        int u = ls + it * 16;                // 0..159, all table-valid
        float w0 = wqA[u * 9 + h];
        float w1 = wqB[u * 9 + h];
        short8 d8 = *(const short8*)&S[(size_t)srow[u] * 256 + c8];
#pragma unroll
        for (int j = 0; j < 8; ++j) {
            float f = sh2f((unsigned short)d8[j]);
            a0[j] += w0 * f;
            a1[j] += w1 * f;
        }
    }
#pragma unroll
    for (int j = 0; j < 8; ++j) {           // combine the wave's two u-slices
        a0[j] += __shfl_xor(a0[j], 32);
        a1[j] += __shfl_xor(a1[j], 32);
    }
    int wv = tid >> 6, lane = tid & 63;
    if (lane < 32) {
        float4 lo0 = {a0[0], a0[1], a0[2], a0[3]}, hi0 = {a0[4], a0[5], a0[6], a0[7]};
        *(float4*)&scrA[wv * 264 + c8]     = lo0;
        *(float4*)&scrA[wv * 264 + c8 + 4] = hi0;
        float4 lo1 = {a1[0], a1[1], a1[2], a1[3]}, hi1 = {a1[4], a1[5], a1[6], a1[7]};
        *(float4*)&scrB[wv * 260 + c8]     = lo1;
        *(float4*)&scrB[wv * 260 + c8 + 4] = hi1;
    }
}

// concurrent reduction of both scratches (512 threads: halves)
DEV void pool_reduce2(const float* scrA, const float* scrB,
                      float* out0, float* out1, int tid) {
    if (tid < 256) {
        float s = 0.f;
#pragma unroll
        for (int q = 0; q < 8; ++q) s += scrA[q * 264 + tid];
        out0[tid] = s;
    } else {
        int t2 = tid - 256;
        float s = 0.f;
#pragma unroll
        for (int q = 0; q < 8; ++q) s += scrB[q * 260 + t2];
        out1[t2] = s;
    }
}

// window means for both t's from the 6-row union; optional per-c scale.
// FIXED 2-rep trip: rep 1 (i = tid+512, up to 1023) loads unconditionally —
// v <= 31 keeps srow indices <= 156 (clamp-valid) — and only the CB stores
// are guarded (R17 sweep recipe).
DEV void wmean2(const u16b* __restrict__ S, const int* srow,
                const float* scale0, const float* scale1,
                u16b* __restrict__ CB, int base, int nb, int tid) {
#pragma unroll
    for (int rep = 0; rep < 2; ++rep) {
        int i = tid + rep * 512;             // 0..1023
        int v = i >> 5, c8 = (i & 31) * 8;
        float s0[8] = {0.f,0.f,0.f,0.f,0.f,0.f,0.f,0.f};
        float s1[8] = {0.f,0.f,0.f,0.f,0.f,0.f,0.f,0.f};
#pragma unroll
        for (int w = 0; w < 6; ++w) {
            short8 d8 = *(const short8*)&S[(size_t)srow[w * 25 + v] * 256 + c8];
#pragma unroll
            for (int j = 0; j < 8; ++j) {
                float f = sh2f((unsigned short)d8[j]);
                if (w < 5)  s0[j] += f;
                if (w >= 1) s1[j] += f;
            }
        }
        if (i < 800) {
            unsigned short o0[8], o1[8];
#pragma unroll
            for (int j = 0; j < 8; ++j) {
                float m0 = s0[j] * 0.2f, m1 = s1[j] * 0.2f;
                if (scale0) { m0 *= scale0[c8 + j]; m1 *= scale1[c8 + j]; }
                o0[j] = f2b(m0); o1[j] = f2b(m1);
            }
            *(uint4*)&CB[((size_t)nb * 25 + v) * 512 + base + c8]       = *(uint4*)o0;
            *(uint4*)&CB[((size_t)(nb + 1) * 25 + v) * 512 + base + c8] = *(uint4*)o1;
        }
    }
}

__global__ __launch_bounds__(512)
void pool_fused2(const u16b* __restrict__ qf, const u16b* __restrict__ kf,
                 const u16b* __restrict__ vf, const u16b* __restrict__ sv,
                 u16b* __restrict__ CB) {
    __shared__ int srow[160];
    __shared__ alignas(16) u16b su[16 * 260];    // q/k su weights; scrB during sweeps
    __shared__ float slog[160 * 19];             // logits; scrA during sweeps
    __shared__ float wqA[160 * 9], wqB[160 * 9];
    __shared__ float spq[2][256], spk[2][256];
    int bid = blockIdx.x;
    int b2 = ((bid & 7) << 7) | (bid >> 3);  // XCD-aware (1024 % 8 == 0)
    int n = b2 >> 5, t0 = (b2 & 31) * 2;
    int nb = n * 64 + t0;
    int tid = threadIdx.x;
    if (tid < 160) {
        int u = tid < 150 ? tid : 149;
        int tl = u / 25, v = u - tl * 25, tt = t0 + tl - 2;
        srow[tid] = ((unsigned)tt < 64u) ? (n * 64 + tt) * 25 + v : 51200;
    }
    // q su rows 0..7 = qa_w raw copy (layout [c*8+h] -> su[h*260+c]); zero wq once
    for (int i = tid; i < 2048; i += 512) {
        int c = i >> 3, h = i & 7;
        su[h * 260 + c] = sv[O_QAW + i];
    }
    for (int i = tid; i < 1440; i += 512) { wqA[i] = 0.f; wqB[i] = 0.f; }
    __syncthreads();

    // ---- q logits (once per union row, MFMA) + both-t softmax ----
    logits_union(qf, su, srow, slog, sv, O_QAB, tid);
    __syncthreads();
    softmax16<0>(slog, wqA, wqB, tid);
    __syncthreads();

    // ---- q sweep (dual scratch; su dead after logits) + qbar same phase ----
    pool_sweep2(qf, srow, wqA, wqB, slog, (float*)su, tid);
    wmean2(qf, srow, nullptr, nullptr, CB, 256, nb, tid);
    __syncthreads();
    pool_reduce2(slog, (float*)su, spq[0], spq[1], tid);
    __syncthreads();

    // ---- k su: rows 0-7 = ka*pq(t0), rows 8-15 = ka*pq(t1) ----
    for (int i = tid; i < 4096; i += 512) {
        int c = i >> 4, h16 = i & 15;
        float w = sh2f(sv[O_KAW + c * 8 + (h16 & 7)]) * spq[h16 >> 3][c];
        su[h16 * 260 + c] = f2b(w);
    }
    __syncthreads();

    // ---- k logits (both t in one pass: cols 0-15) + softmax ----
    logits_union(kf, su, srow, slog, sv, O_KAB, tid);
    __syncthreads();
    softmax16<1>(slog, wqA, wqB, tid);
    __syncthreads();

    // ---- k sweep (su dead after logits -> scrB) ----
    pool_sweep2(kf, srow, wqA, wqB, slog, (float*)su, tid);
    __syncthreads();
    pool_reduce2(slog, (float*)su, spk[0], spk[1], tid);
    __syncthreads();

    // ---- vbarP for both t -> CB cols 0..255 ----
    wmean2(vf, srow, spk[0], spk[1], CB, 0, nb, tid);
}

// ---------------------------------------------------------------------------
extern "C" void kernel_launch(void* const* d_in, const int* in_sizes, int n_in,
                              void* d_out, int out_size, void* d_ws, size_t ws_size,
                              hipStream_t stream) {
    (void)in_sizes; (void)n_in; (void)out_size; (void)ws_size;
    const void* x    = d_in[0];
    const void* ln1g = d_in[1];  const void* ln1b = d_in[2];
    const void* q_w  = d_in[3];  const void* q_b  = d_in[4];
    const void* qa_w = d_in[5];  const void* qa_b = d_in[6];
    const void* k_w  = d_in[7];  const void* k_b  = d_in[8];
    const void* ka_w = d_in[9];  const void* ka_b = d_in[10];
    const void* v_w  = d_in[11]; const void* v_b  = d_in[12];
    const void* t_w  = d_in[13]; const void* t_b  = d_in[14];
    const void* p_w  = d_in[15]; const void* p_b  = d_in[16];
    const void* ffng = d_in[17]; const void* ffnb = d_in[18];
    const void* w1   = d_in[19]; const void* b1   = d_in[20];
    const void* w2   = d_in[21]; const void* b2   = d_in[22];

    char* ws = (char*)d_ws;
    size_t off = 0;
    auto alloc = [&](size_t bytes) { void* p = ws + off; off += (bytes + 255) & ~(size_t)255; return p; };
    const size_t RPAD = 51328;           // 51200 valid rows + 128 pad rows
    int*    flag = (int*)alloc(256);
    u16b*   sv   = (u16b*)alloc(8192 * 2);                // packed small vectors
    u16b*   wT   = (u16b*)alloc((size_t)7 * 65536 * 2);   // qT kT vT pT tT w1T w2T
    u16b*   cW   = (u16b*)alloc((size_t)256 * 512 * 2);   // comboWt: [TP^T | p_w^T]
    u16b*   xT   = (u16b*)alloc(RPAD * 256 * 2);
    u16b*   Bq   = (u16b*)alloc(RPAD * 256 * 2);          // q_full -> h1
    u16b*   Bk   = (u16b*)alloc(RPAD * 256 * 2);
    u16b*   Bv   = (u16b*)alloc(RPAD * 256 * 2);
    u16b*   CB   = (u16b*)alloc((size_t)51200 * 512 * 2); // [vbarP | qbar]
    u16b*   att  = (u16b*)alloc((size_t)51200 * 256 * 2); // att
    float2* st2p = (float2*)alloc((size_t)2 * 51200 * 8); // att partial stats (2 n-blocks)

    u16b* pT  = wT + 3 * 65536;
    u16b* tT  = wT + 4 * 65536;
    u16b* w1T = wT + 5 * 65536;
    u16b* w2T = wT + 6 * 65536;

    // 0) dtype detection
    detect_k<<<1, 256, 0, stream>>>((const unsigned*)x, flag);
    // 1) small-vector conversion
    VecTab tab;
    const void* vp[15] = {ln1g, ln1b, q_b, k_b, v_b, t_b, p_b, ffng, ffnb, b1, b2, qa_b, ka_b, qa_w, ka_w};
    const int vo[15] = {O_LN1G, O_LN1B, O_QB, O_KB, O_VB, O_TB, O_PB, O_FFNG, O_FFNB, O_B1, O_B2, O_QAB, O_KAB, O_QAW, O_KAW};
    const int vn[15] = {256, 256, 256, 256, 256, 256, 256, 256, 256, 256, 256, 8, 8, 2048, 2048};
    for (int i = 0; i < 15; ++i) { tab.p[i] = vp[i]; tab.off[i] = vo[i]; tab.n[i] = vn[i]; }
    convert_vecs_k<<<15, 256, 0, stream>>>(tab, flag, sv);

    dim3 tb(32, 8);
    // 2) weight transposes: slices 0-6 -> wT slabs; slice 7: p_w^T -> cW cols 256.. (stride 512)
    W8 wt;
    const void* wsrc[8] = {q_w, k_w, v_w, p_w, t_w, w1, w2, p_w};
    for (int i = 0; i < 8; ++i) {
        wt.p[i] = wsrc[i];
        wt.dstoff[i] = (i < 7) ? (unsigned)(i * 65536) : (unsigned)((cW + 256) - wT);
        wt.rstride[i] = (i < 7) ? 256u : 512u;
    }
    wtrans_k<<<dim3(8, 8, 8), tb, 0, stream>>>(wt, wT, flag);
    // 3) cvec = t_b @ p_w + p_b  (into sv+O_CV)
    cvec_k<<<1, 256, 0, stream>>>(pT, sv);
    // 4) TP^T into cW cols 0..255:  out[m,k] = sum_j pT[m,j] tT[k,j] = (t_w@p_w)[k,m]
    gemm256<0, 0><<<dim3(4, 2), 256, 0, stream>>>(pT, 256, 256, tT, nullptr, nullptr,
                                                  cW, 512, nullptr, nullptr, nullptr, nullptr,
                                                  nullptr, nullptr);
    // 5) x (n, 256, 1600) -> xT (n, 1600, 256)
    transpose_in_k<<<dim3(50, 8, 32), 256, 0, stream>>>(x, xT, 256, 1600, flag);
    // 6) fused q/k/v GEMM with inline LN, XCD-pinned panel map (XY=2):
    //    all 6 n-blocks of one A-panel run on ONE XCD -> A fetched once.
    gemm256<4, 1, 2><<<4848, 256, 0, stream>>>(xT, 256, 256, wT, sv + O_QB, nullptr,
                                               Bq, RPAD * 256, nullptr, nullptr,
                                               sv + O_LN1G, sv + O_LN1B, nullptr, nullptr);
    // 7) fused pools + window means (t-pair tiled) -> CB
    pool_fused2<<<1024, 512, 0, stream>>>(Bq, Bk, Bv, sv, CB);
    // 8) att = CB @ comboWt^T + cvec + x_residual (K=512); + partial LN stats -> st2p
    gemm256<2, 0, 1, 1><<<dim3(2, 800), 256, 0, stream>>>(CB, 512, 512, cW, sv + O_CV, xT,
                                                          att, 256, nullptr, nullptr,
                                                          nullptr, nullptr, st2p, nullptr);
    // 9) h1 = gelu(LN(att) @ w1 + b1); LN stats combined from st2p halves (into Bq)
    gemm256<3, 2, 1><<<dim3(2, 800), 256, 0, stream>>>(att, 256, 256, w1T, sv + O_B1, nullptr,
                                                       Bq, 256, st2p, st2p + 51200,
                                                       sv + O_FFNG, sv + O_FFNB, nullptr, nullptr);
    // 10) y = h1 @ w2 + b2 + att, stored transposed directly to output
    gemm256<5, 0, 1><<<dim3(2, 800), 256, 0, stream>>>(Bq, 256, 256, w2T, sv + O_B2, att,
                                                       (u16b*)d_out, 0, nullptr, nullptr,
                                                       nullptr, nullptr, nullptr, flag);
}